// Round 5
// baseline (811.697 us; speedup 1.0000x reference)
//
#include <hip/hip_runtime.h>
#include <math.h>

// Problem constants (fixed by reference setup)
#define S_LEN   1024
#define BATCH   2
#define DMODEL  1024
#define NHEADS  16
#define HDIM    64
#define BHEADS  32          // BATCH*NHEADS
#define LP1     4           // 1 + L layers
#define ROWS_PL 2048        // S*B rows per layer

typedef __attribute__((ext_vector_type(8)))  short bf16x8;   // 8 bf16 = 4 VGPRs
typedef __attribute__((ext_vector_type(4)))  float f32x4;
typedef __attribute__((ext_vector_type(16))) float f32x16;

__device__ inline ushort bf16_rne(float a) {
    unsigned u = __float_as_uint(a);
    return (ushort)((u + 0x7FFFu + ((u >> 16) & 1u)) >> 16);
}
__device__ inline float bf16_up(ushort h) { return __uint_as_float(((unsigned)h) << 16); }
__device__ inline void split_bf16(float a, ushort &hi, ushort &lo) {
    hi = bf16_rne(a);
    lo = bf16_rne(a - bf16_up(hi));
}

// ---------------------------------------------------------------------------
// One-shot pre-split: Xs = [x ; layer_outputs] -> hi bf16 plane (A-lo term
// dropped in GEMMs); weights -> hi+lo planes. Single launch, z-demuxed.
// ---------------------------------------------------------------------------
__global__ __launch_bounds__(256)
void presplit(const float* __restrict__ x, const float* __restrict__ lo,
              const float* __restrict__ Wq, const float* __restrict__ Wk,
              const float* __restrict__ Wv, const float* __restrict__ Wo,
              ushort* __restrict__ XsH, ushort* __restrict__ WH,
              ushort* __restrict__ WL)
{
    const int z = blockIdx.z;
    const float* src; ushort* dh; ushort* dl = nullptr; int n;
    if (z == 0)      { src = x;  dh = XsH;           n = 2097152; }
    else if (z == 1) { src = lo; dh = XsH + 2097152; n = 6291456; }
    else {
        const float* wsrc[4] = { Wq, Wk, Wv, Wo };
        src = wsrc[z - 2];
        dh = WH + (size_t)(z - 2) * 1048576;
        dl = WL + (size_t)(z - 2) * 1048576;
        n = 1048576;
    }
    const int i = (blockIdx.x * 256 + threadIdx.x) * 8;
    if (i >= n) return;
    float v[8];
    *(float4*)&v[0] = *(const float4*)(src + i);
    *(float4*)&v[4] = *(const float4*)(src + i + 4);
    ushort h[8];
    #pragma unroll
    for (int j = 0; j < 8; ++j) h[j] = bf16_rne(v[j]);
    *(uint4*)(dh + i) = *(uint4*)h;
    if (dl) {
        ushort l[8];
        #pragma unroll
        for (int j = 0; j < 8; ++j) l[j] = bf16_rne(v[j] - bf16_up(h[j]));
        *(uint4*)(dl + i) = *(uint4*)l;
    }
}

// ---------------------------------------------------------------------------
// bf16-plane GEMM: C[M,N] = A_hi[M,1024] @ (W_hi+W_lo)[N,1024]^T + bias[N]
// 2-term MFMA (ah*bh + ah*bl). BM=BN=128, BK=32, 256 thr (2x2 waves, 4x4
// frags each). Staging = pure uint4 copies (no conversion VALU).
// AFP32: A is fp32, rne-rounded to hi during staging (O-proj from ybuf).
// MODE 1: fp32 row-major out[m][n]
// MODE 2: split bf16 hi/lo planes at [l*32+b*16+h][s][e]   (Q and K)
// MODE 3: split bf16 hi/lo planes at [l*32+b*16+h][e][s] via LDS transpose (V^T)
// ---------------------------------------------------------------------------
template<int MODE, bool AFP32>
__global__ __launch_bounds__(256)
void proj_bf16(const ushort* __restrict__ Abf, const float* __restrict__ Af,
               const ushort* __restrict__ Bhg, const ushort* __restrict__ Blg,
               const float* __restrict__ bias,
               float* __restrict__ outf, ushort* __restrict__ outh,
               ushort* __restrict__ outl)
{
    constexpr int MI = 4, NJ = 4;
    constexpr int STAGE_U = 3 * 4096;                       // Ah, Bh, Bl
    constexpr int TRANS_U = (MODE == 3) ? 128 * 130 : 0;
    constexpr int SMEM_U  = STAGE_U > TRANS_U ? STAGE_U : TRANS_U;

    __shared__ ushort smem[SMEM_U];
    ushort* Ah = smem;
    ushort* Bh = smem + 4096;
    ushort* Bl = smem + 8192;

    const int t  = threadIdx.x;
    const int m0 = blockIdx.y * 128, n0 = blockIdx.x * 128;

    const int wave = t >> 6, lane = t & 63;
    const int quad = lane >> 4, r = lane & 15;
    const int wm = wave & 1, wn = wave >> 1;
    const int mBase = wm * 64, nBase = wn * 64;

    const int srow = t >> 1, seg = t & 1;   // staging: 1 row, 16 k per thread

    f32x4 acc[MI][NJ];
    #pragma unroll
    for (int i = 0; i < MI; ++i)
        #pragma unroll
        for (int j = 0; j < NJ; ++j) acc[i][j] = (f32x4){0.f, 0.f, 0.f, 0.f};

    for (int k0 = 0; k0 < DMODEL; k0 += 32) {
        uint4 av[2], bhv[2], blv[2];
        if (AFP32) {
            const float* p = Af + (size_t)(m0 + srow) * DMODEL + k0 + seg * 16;
            float fv[16];
            #pragma unroll
            for (int c = 0; c < 4; ++c) *(float4*)&fv[c * 4] = *(const float4*)(p + c * 4);
            ushort hv[16];
            #pragma unroll
            for (int j = 0; j < 16; ++j) hv[j] = bf16_rne(fv[j]);
            av[0] = *(uint4*)&hv[0]; av[1] = *(uint4*)&hv[8];
        } else {
            const ushort* p = Abf + (size_t)(m0 + srow) * DMODEL + k0 + seg * 16;
            av[0] = *(const uint4*)p; av[1] = *(const uint4*)(p + 8);
        }
        {
            const ushort* p = Bhg + (size_t)(n0 + srow) * DMODEL + k0 + seg * 16;
            bhv[0] = *(const uint4*)p; bhv[1] = *(const uint4*)(p + 8);
            const ushort* q = Blg + (size_t)(n0 + srow) * DMODEL + k0 + seg * 16;
            blv[0] = *(const uint4*)q; blv[1] = *(const uint4*)(q + 8);
        }
        __syncthreads();   // previous iteration's frag reads done
        {
            ushort* d = &Ah[srow * 32 + seg * 16];
            *(uint4*)d = av[0]; *(uint4*)(d + 8) = av[1];
            ushort* e = &Bh[srow * 32 + seg * 16];
            *(uint4*)e = bhv[0]; *(uint4*)(e + 8) = bhv[1];
            ushort* f = &Bl[srow * 32 + seg * 16];
            *(uint4*)f = blv[0]; *(uint4*)(f + 8) = blv[1];
        }
        __syncthreads();
        bf16x8 fa[MI], fbh[NJ], fbl[NJ];
        #pragma unroll
        for (int i = 0; i < MI; ++i)
            fa[i] = *(const bf16x8*)&Ah[(mBase + i * 16 + r) * 32 + quad * 8];
        #pragma unroll
        for (int j = 0; j < NJ; ++j) {
            fbh[j] = *(const bf16x8*)&Bh[(nBase + j * 16 + r) * 32 + quad * 8];
            fbl[j] = *(const bf16x8*)&Bl[(nBase + j * 16 + r) * 32 + quad * 8];
        }
        #pragma unroll
        for (int i = 0; i < MI; ++i)
            #pragma unroll
            for (int j = 0; j < NJ; ++j) {
                acc[i][j] = __builtin_amdgcn_mfma_f32_16x16x32_bf16(fa[i], fbh[j], acc[i][j], 0, 0, 0);
                acc[i][j] = __builtin_amdgcn_mfma_f32_16x16x32_bf16(fa[i], fbl[j], acc[i][j], 0, 0, 0);
            }
    }

    const int cn = lane & 15;

    if (MODE == 3) {
        // ---- V^T epilogue: LDS transpose, coalesced 128 B stores/thread ----
        ushort* T = smem;   // [128][130]
        __syncthreads();    // staging reads done before overwrite
        #pragma unroll
        for (int p = 0; p < 2; ++p) {
            #pragma unroll
            for (int j = 0; j < NJ; ++j) {
                const int nloc = nBase + j * 16 + cn;
                const float bv = bias[n0 + nloc];
                #pragma unroll
                for (int i = 0; i < MI; ++i) {
                    #pragma unroll
                    for (int g = 0; g < 4; ++g) {
                        const int mloc = mBase + i * 16 + quad * 4 + g;
                        ushort hi, lov; split_bf16(acc[i][j][g] + bv, hi, lov);
                        T[nloc * 130 + mloc] = p ? lov : hi;
                    }
                }
            }
            __syncthreads();
            {
                const int nloc = t >> 1, bsel = t & 1;
                const int n = n0 + nloc, h = n >> 6, e = n & 63;
                const int lyr = m0 >> 11, s0g = (m0 & 2047) >> 1;
                const int bhI = lyr * 32 + bsel * 16 + h;
                ushort* plane = p ? outl : outh;
                ushort* dst = plane + ((size_t)bhI * HDIM + e) * S_LEN + s0g;
                #pragma unroll
                for (int c = 0; c < 8; ++c) {
                    ushort tmp[8];
                    #pragma unroll
                    for (int j = 0; j < 8; ++j)
                        tmp[j] = T[nloc * 130 + 2 * (c * 8 + j) + bsel];
                    *(uint4*)(dst + c * 8) = *(uint4*)tmp;
                }
            }
            __syncthreads();
        }
        return;
    }

    #pragma unroll
    for (int j = 0; j < NJ; ++j) {
        const int n = n0 + nBase + j * 16 + cn;
        const float bv = bias[n];
        #pragma unroll
        for (int i = 0; i < MI; ++i) {
            const int mrow = m0 + mBase + i * 16 + quad * 4;
            #pragma unroll
            for (int g = 0; g < 4; ++g) {
                const float val = acc[i][j][g] + bv;
                const int m = mrow + g;
                if (MODE == 1) {
                    outf[(size_t)m * DMODEL + n] = val;
                } else {   // MODE == 2: split planes [l*32+b*16+h][s][e]
                    const int l = m >> 11, rem = m & 2047;
                    const int s = rem >> 1, b = rem & 1;
                    const int h = n >> 6, e = n & 63;
                    const int bh = l * 32 + b * 16 + h;
                    ushort hi, lov; split_bf16(val, hi, lov);
                    const size_t idx = (((size_t)bh * S_LEN) + s) * HDIM + e;
                    outh[idx] = hi; outl[idx] = lov;
                }
            }
        }
    }
}

// ---------------------------------------------------------------------------
// MFMA flash attention. Block = 4 waves, each wave owns q=32. Grid
// (8, 32, 4) = 1024 blocks (~4/CU); LDS 32 KB (per-wave P tiles only).
//   A-frag (32x32x16): lane holds A[m=lid][k=half*8+j]
//   C/D:               col=lid, row=(reg&3)+8*(reg>>2)+4*half
// Q from pre-split planes (no conversion VALU). K/V frags direct from
// global (L1-shared across the 4 waves). No-max softmax, linear row sums,
// one shuffle-reduce at the end, atomicAdd epilogue into ybuf[s][b][d].
// ---------------------------------------------------------------------------
__global__ __launch_bounds__(256, 3)
void attn_mfma(const ushort* __restrict__ qhg, const ushort* __restrict__ qlg,
               const ushort* __restrict__ kh, const ushort* __restrict__ kl,
               const ushort* __restrict__ vth, const ushort* __restrict__ vtl,
               const float* __restrict__ lwraw, float* __restrict__ yb)
{
    __shared__ uint Ps[4][2048];   // [wave][k*32+swz]  = 32 KB

    const int t    = threadIdx.x;
    const int wv   = t >> 6, lane = t & 63;
    const int half = lane >> 5, lid = lane & 31;
    const int bh = blockIdx.y, l = blockIdx.z;
    const int qbase = blockIdx.x * 128 + wv * 32;
    const float SCL = 0.125f * 1.44269504088896340736f;  // hd^-0.5 * log2(e)

    float wl;
    {
        float v[LP1], wm = -3.0e38f;
        #pragma unroll
        for (int i = 0; i < LP1; ++i) { v[i] = lwraw[i]; wm = fmaxf(wm, v[i]); }
        float ws = 0.f;
        #pragma unroll
        for (int i = 0; i < LP1; ++i) { v[i] = __expf(v[i] - wm); ws += v[i]; }
        wl = v[l] / ws;
    }

    // Q A-frags straight from pre-split planes
    bf16x8 qh[4], ql[4];
    {
        const size_t qoff = (((size_t)bh * S_LEN) + qbase + lid) * HDIM + half * 8;
        #pragma unroll
        for (int es = 0; es < 4; ++es) {
            qh[es] = *(const bf16x8*)(qhg + qoff + es * 16);
            ql[es] = *(const bf16x8*)(qlg + qoff + es * 16);
        }
    }

    f32x16 o[2];
    #pragma unroll
    for (int d = 0; d < 2; ++d)
        #pragma unroll
        for (int i = 0; i < 16; ++i) o[d][i] = 0.f;
    float ls[16];
    #pragma unroll
    for (int i = 0; i < 16; ++i) ls[i] = 0.f;

    const size_t kvbase = (size_t)(l * BHEADS + bh) * S_LEN * HDIM;

    for (int kt = 0; kt < 16; ++kt) {
        // ---- S = Q K^T, one 32-key column at a time ----
        #pragma unroll
        for (int kc = 0; kc < 2; ++kc) {
            f32x16 sa;
            #pragma unroll
            for (int i = 0; i < 16; ++i) sa[i] = 0.f;

            #pragma unroll
            for (int es = 0; es < 4; ++es) {
                const size_t off = kvbase + (size_t)(kt * 64 + kc * 32 + lid) * HDIM
                                 + es * 16 + half * 8;
                const bf16x8 kbh = *(const bf16x8*)(kh + off);
                const bf16x8 kbl = *(const bf16x8*)(kl + off);
                sa = __builtin_amdgcn_mfma_f32_32x32x16_bf16(qh[es], kbh, sa, 0, 0, 0);
                sa = __builtin_amdgcn_mfma_f32_32x32x16_bf16(qh[es], kbl, sa, 0, 0, 0);
                sa = __builtin_amdgcn_mfma_f32_32x32x16_bf16(ql[es], kbh, sa, 0, 0, 0);
            }

            // P = exp2(s*SCL); row sums; swizzled per-wave LDS write
            const int k = kc * 32 + lid;
            uint pu[16];
            #pragma unroll
            for (int r = 0; r < 16; ++r) {
                const float p = exp2f(sa[r] * SCL);
                ls[r] += p;
                ushort hi, lov; split_bf16(p, hi, lov);
                pu[r] = (uint)hi | ((uint)lov << 16);
            }
            #pragma unroll
            for (int rq = 0; rq < 4; ++rq) {
                const int cq = 2 * rq + half;
                const int cs = cq ^ (k & 7);
                uint4 v = { pu[rq * 4 + 0], pu[rq * 4 + 1], pu[rq * 4 + 2], pu[rq * 4 + 3] };
                ((uint4*)Ps[wv])[k * 8 + cs] = v;
            }
        }

        // ---- O += P V ----
        #pragma unroll
        for (int ks = 0; ks < 4; ++ks) {
            ushort phv[8], plv[8];
            #pragma unroll
            for (int j = 0; j < 8; ++j) {
                const int k = ks * 16 + half * 8 + j;   // k&7 == j
                const uint w = Ps[wv][k * 32 + (((lid >> 2) ^ j) << 2) + (lid & 3)];
                phv[j] = (ushort)(w & 0xffffu);
                plv[j] = (ushort)(w >> 16);
            }
            const bf16x8 ph = *(bf16x8*)phv;
            const bf16x8 pl = *(bf16x8*)plv;
            #pragma unroll
            for (int dg = 0; dg < 2; ++dg) {
                const size_t off = kvbase + (size_t)(dg * 32 + lid) * S_LEN
                                 + kt * 64 + ks * 16 + half * 8;
                const bf16x8 vbh = *(const bf16x8*)(vth + off);
                const bf16x8 vbl = *(const bf16x8*)(vtl + off);
                o[dg] = __builtin_amdgcn_mfma_f32_32x32x16_bf16(ph, vbh, o[dg], 0, 0, 0);
                o[dg] = __builtin_amdgcn_mfma_f32_32x32x16_bf16(ph, vbl, o[dg], 0, 0, 0);
                o[dg] = __builtin_amdgcn_mfma_f32_32x32x16_bf16(pl, vbh, o[dg], 0, 0, 0);
            }
        }
    }

    // ---- row-sum reduction across the 32 key-columns ----
    #pragma unroll
    for (int r = 0; r < 16; ++r) {
        float v = ls[r];
        #pragma unroll
        for (int off = 1; off < 32; off <<= 1) v += __shfl_xor(v, off, 32);
        ls[r] = v;
    }

    // ---- epilogue: atomicAdd w_l * O / ls into ybuf[s][b][d] ----
    const int b = bh >> 4, hh = bh & 15;
    #pragma unroll
    for (int r = 0; r < 16; ++r) {
        const int q = qbase + 8 * (r >> 2) + 4 * half + (r & 3);
        const float sc = wl / ls[r];
        #pragma unroll
        for (int dg = 0; dg < 2; ++dg) {
            const int d = hh * HDIM + dg * 32 + lid;
            atomicAdd(&yb[((size_t)q * BATCH + b) * DMODEL + d], o[dg][r] * sc);
        }
    }
}

// ---------------------------------------------------------------------------
extern "C" void kernel_launch(void* const* d_in, const int* in_sizes, int n_in,
                              void* d_out, int out_size, void* d_ws, size_t ws_size,
                              hipStream_t stream) {
    const float* x  = (const float*)d_in[0];
    const float* lo = (const float*)d_in[1];
    const float* Wq = (const float*)d_in[2];
    const float* bq = (const float*)d_in[3];
    const float* Wk = (const float*)d_in[4];
    const float* bk = (const float*)d_in[5];
    const float* Wv = (const float*)d_in[6];
    const float* bv = (const float*)d_in[7];
    const float* Wo = (const float*)d_in[8];
    const float* bo = (const float*)d_in[9];
    const float* lw = (const float*)d_in[10];
    float* out = (float*)d_out;

    char* ws = (char*)d_ws;
    ushort* XsH  = (ushort*)(ws);                          // 16,777,216 B
    ushort* WH   = (ushort*)(ws + 16777216);               //  8,388,608 B
    ushort* WL   = (ushort*)(ws + 25165824);               //  8,388,608 B
    ushort* qhb  = (ushort*)(ws + 33554432);               //  4,194,304 B
    ushort* qlb  = (ushort*)(ws + 37748736);               //  4,194,304 B
    ushort* khb  = (ushort*)(ws + 41943040);               // 16,777,216 B
    ushort* klb  = (ushort*)(ws + 58720256);               // 16,777,216 B
    ushort* vthb = (ushort*)(ws + 75497472);               // 16,777,216 B
    ushort* vtlb = (ushort*)(ws + 92274688);               // 16,777,216 B
    float*  ybuf = (float*)(ws + 109051904);               //  8,388,608 B
    // total 117,440,512 B

    hipMemsetAsync(ybuf, 0, (size_t)ROWS_PL * DMODEL * sizeof(float), stream);

    dim3 blk(256);
    // pre-split activations (hi) and weights (hi+lo)
    presplit<<<dim3(3072, 1, 6), blk, 0, stream>>>(x, lo, Wq, Wk, Wv, Wo, XsH, WH, WL);
    // Q projection -> split planes [b*16+h][s][e]   (M = 2048)
    proj_bf16<2, false><<<dim3(8, 16), blk, 0, stream>>>(XsH, nullptr, WH, WL, bq, nullptr, qhb, qlb);
    // K projection -> split planes [l*32+b*16+h][s][e]   (M = 8192)
    proj_bf16<2, false><<<dim3(8, 64), blk, 0, stream>>>(XsH, nullptr, WH + 1048576, WL + 1048576, bk, nullptr, khb, klb);
    // V projection -> split planes transposed [l*32+b*16+h][e][s]
    proj_bf16<3, false><<<dim3(8, 64), blk, 0, stream>>>(XsH, nullptr, WH + 2097152, WL + 2097152, bv, nullptr, vthb, vtlb);
    // attention: 4 waves/block, wave = q32, grid (8, 32, 4)
    attn_mfma<<<dim3(8, 32, LP1), blk, 0, stream>>>(qhb, qlb, khb, klb, vthb, vtlb, lw, ybuf);
    // output projection (fp32 A rounded to bf16-hi during staging)
    proj_bf16<1, true><<<dim3(8, 16), blk, 0, stream>>>(nullptr, ybuf, WH + 3145728, WL + 3145728, bo, out, nullptr, nullptr);
}

// Round 6
// 555.548 us; speedup vs baseline: 1.4611x; 1.4611x over previous
//
#include <hip/hip_runtime.h>
#include <math.h>

// Problem constants (fixed by reference setup)
#define S_LEN   1024
#define BATCH   2
#define DMODEL  1024
#define NHEADS  16
#define HDIM    64
#define BHEADS  32          // BATCH*NHEADS
#define LP1     4           // 1 + L layers
#define ROWS_PL 2048        // S*B rows per layer

typedef __attribute__((ext_vector_type(8)))  short bf16x8;   // 8 bf16 = 4 VGPRs
typedef __attribute__((ext_vector_type(4)))  float f32x4;
typedef __attribute__((ext_vector_type(16))) float f32x16;

__device__ inline ushort bf16_rne(float a) {
    unsigned u = __float_as_uint(a);
    return (ushort)((u + 0x7FFFu + ((u >> 16) & 1u)) >> 16);
}
__device__ inline float bf16_up(ushort h) { return __uint_as_float(((unsigned)h) << 16); }
__device__ inline void split_bf16(float a, ushort &hi, ushort &lo) {
    hi = bf16_rne(a);
    lo = bf16_rne(a - bf16_up(hi));
}

// ---------------------------------------------------------------------------
// One-shot pre-split: Xs = [x ; layer_outputs] -> hi bf16 plane;
// weights -> hi+lo planes. Single launch, z-demuxed.
// ---------------------------------------------------------------------------
__global__ __launch_bounds__(256)
void presplit(const float* __restrict__ x, const float* __restrict__ lo,
              const float* __restrict__ Wq, const float* __restrict__ Wk,
              const float* __restrict__ Wv, const float* __restrict__ Wo,
              ushort* __restrict__ XsH, ushort* __restrict__ WH,
              ushort* __restrict__ WL)
{
    const int z = blockIdx.z;
    const float* src; ushort* dh; ushort* dl = nullptr; int n;
    if (z == 0)      { src = x;  dh = XsH;           n = 2097152; }
    else if (z == 1) { src = lo; dh = XsH + 2097152; n = 6291456; }
    else {
        const float* wsrc[4] = { Wq, Wk, Wv, Wo };
        src = wsrc[z - 2];
        dh = WH + (size_t)(z - 2) * 1048576;
        dl = WL + (size_t)(z - 2) * 1048576;
        n = 1048576;
    }
    const int i = (blockIdx.x * 256 + threadIdx.x) * 8;
    if (i >= n) return;
    float v[8];
    *(float4*)&v[0] = *(const float4*)(src + i);
    *(float4*)&v[4] = *(const float4*)(src + i + 4);
    ushort h[8];
    #pragma unroll
    for (int j = 0; j < 8; ++j) h[j] = bf16_rne(v[j]);
    *(uint4*)(dh + i) = *(uint4*)h;
    if (dl) {
        ushort l[8];
        #pragma unroll
        for (int j = 0; j < 8; ++j) l[j] = bf16_rne(v[j] - bf16_up(h[j]));
        *(uint4*)(dl + i) = *(uint4*)l;
    }
}

// ---------------------------------------------------------------------------
// bf16-plane GEMM: C[M,N] = A_hi[M,1024] @ (W_hi+W_lo)[N,1024]^T + bias[N]
// 2-term MFMA (ah*bh + ah*bl). BM = MI*32 (MI=4 -> 128, MI=2 -> 64), BN=128,
// BK=32, 256 thr (2x2 waves). Staging = pure uint4 copies.
// AFP32: A fp32, rne-rounded to hi during staging (O-proj from ybuf).
// MODE 1: fp32 row-major out[m][n]                          (O)
// MODE 2: split bf16 hi+lo planes at [l*32+b*16+h][s][e]    (Q)
// MODE 4: hi-only plane at [l*32+b*16+h][s][e]              (K)
// MODE 5: hi-only plane at [l*32+b*16+h][e][s] via LDS transpose (V^T, MI=4)
// ---------------------------------------------------------------------------
template<int MI, int MODE, bool AFP32>
__global__ __launch_bounds__(256)
void proj_bf16(const ushort* __restrict__ Abf, const float* __restrict__ Af,
               const ushort* __restrict__ Bhg, const ushort* __restrict__ Blg,
               const float* __restrict__ bias,
               float* __restrict__ outf, ushort* __restrict__ outh)
{
    constexpr int BM = MI * 32;
    constexpr int NJ = 4;
    constexpr int STAGE_U = BM * 32 + 8192;
    constexpr int TRANS_U = (MODE == 5) ? 128 * 130 : 0;
    constexpr int SMEM_U  = STAGE_U > TRANS_U ? STAGE_U : TRANS_U;

    __shared__ ushort smem[SMEM_U];
    ushort* Ah = smem;
    ushort* Bh = smem + BM * 32;
    ushort* Bl = Bh + 4096;

    const int t  = threadIdx.x;
    const int m0 = blockIdx.y * BM, n0 = blockIdx.x * 128;

    const ushort* Abase = AFP32 ? nullptr : (Abf + (size_t)m0 * DMODEL);
    const float*  Afb   = AFP32 ? (Af + (size_t)m0 * DMODEL) : nullptr;
    const ushort* Bbh = Bhg + (size_t)n0 * DMODEL;
    const ushort* Bbl = Blg + (size_t)n0 * DMODEL;

    const int wave = t >> 6, lane = t & 63;
    const int quad = lane >> 4, r = lane & 15;
    const int wm = wave & 1, wn = wave >> 1;
    const int mBase = wm * MI * 16, nBase = wn * 64;

    // A staging geometry: ACH ushorts/thread
    constexpr int ACH = BM * 32 / 256;        // 16 (MI=4) or 8 (MI=2)
    constexpr int TPR = 32 / ACH;             // threads per A row: 2 or 4
    const int arow = t / TPR, aoff = (t % TPR) * ACH;
    const int brow = t >> 1, boff = (t & 1) * 16;

    f32x4 acc[MI][NJ];
    #pragma unroll
    for (int i = 0; i < MI; ++i)
        #pragma unroll
        for (int j = 0; j < NJ; ++j) acc[i][j] = (f32x4){0.f, 0.f, 0.f, 0.f};

    for (int k0 = 0; k0 < DMODEL; k0 += 32) {
        uint4 av[ACH / 8], bhv[2], blv[2];
        if (AFP32) {
            const float* p = Afb + (size_t)arow * DMODEL + k0 + aoff;
            #pragma unroll
            for (int c = 0; c < ACH / 8; ++c) {
                float fv[8];
                *(float4*)&fv[0] = *(const float4*)(p + c * 8);
                *(float4*)&fv[4] = *(const float4*)(p + c * 8 + 4);
                ushort hv[8];
                #pragma unroll
                for (int j = 0; j < 8; ++j) hv[j] = bf16_rne(fv[j]);
                av[c] = *(uint4*)hv;
            }
        } else {
            const ushort* p = Abase + (size_t)arow * DMODEL + k0 + aoff;
            #pragma unroll
            for (int c = 0; c < ACH / 8; ++c) av[c] = *(const uint4*)(p + c * 8);
        }
        {
            const ushort* p = Bbh + (size_t)brow * DMODEL + k0 + boff;
            bhv[0] = *(const uint4*)p; bhv[1] = *(const uint4*)(p + 8);
            const ushort* q = Bbl + (size_t)brow * DMODEL + k0 + boff;
            blv[0] = *(const uint4*)q; blv[1] = *(const uint4*)(q + 8);
        }
        __syncthreads();   // previous iteration's frag reads done
        {
            ushort* d = &Ah[arow * 32 + aoff];
            #pragma unroll
            for (int c = 0; c < ACH / 8; ++c) *(uint4*)(d + c * 8) = av[c];
            ushort* e = &Bh[brow * 32 + boff];
            *(uint4*)e = bhv[0]; *(uint4*)(e + 8) = bhv[1];
            ushort* f = &Bl[brow * 32 + boff];
            *(uint4*)f = blv[0]; *(uint4*)(f + 8) = blv[1];
        }
        __syncthreads();
        bf16x8 fa[MI], fbh[NJ], fbl[NJ];
        #pragma unroll
        for (int i = 0; i < MI; ++i)
            fa[i] = *(const bf16x8*)&Ah[(mBase + i * 16 + r) * 32 + quad * 8];
        #pragma unroll
        for (int j = 0; j < NJ; ++j) {
            fbh[j] = *(const bf16x8*)&Bh[(nBase + j * 16 + r) * 32 + quad * 8];
            fbl[j] = *(const bf16x8*)&Bl[(nBase + j * 16 + r) * 32 + quad * 8];
        }
        #pragma unroll
        for (int i = 0; i < MI; ++i)
            #pragma unroll
            for (int j = 0; j < NJ; ++j) {
                acc[i][j] = __builtin_amdgcn_mfma_f32_16x16x32_bf16(fa[i], fbh[j], acc[i][j], 0, 0, 0);
                acc[i][j] = __builtin_amdgcn_mfma_f32_16x16x32_bf16(fa[i], fbl[j], acc[i][j], 0, 0, 0);
            }
    }

    const int cn = lane & 15;

    if (MODE == 5) {
        // ---- V^T epilogue: hi-only LDS transpose, 128 B coalesced stores ----
        ushort* T = smem;   // [128][130]
        __syncthreads();
        #pragma unroll
        for (int j = 0; j < NJ; ++j) {
            const int nloc = nBase + j * 16 + cn;
            const float bv = bias[n0 + nloc];
            #pragma unroll
            for (int i = 0; i < MI; ++i) {
                #pragma unroll
                for (int g = 0; g < 4; ++g) {
                    const int mloc = mBase + i * 16 + quad * 4 + g;
                    T[nloc * 130 + mloc] = bf16_rne(acc[i][j][g] + bv);
                }
            }
        }
        __syncthreads();
        {
            const int nloc = t >> 1, bsel = t & 1;
            const int n = n0 + nloc, h = n >> 6, e = n & 63;
            const int lyr = m0 >> 11, s0g = (m0 & 2047) >> 1;
            const int bhI = lyr * 32 + bsel * 16 + h;
            ushort* dst = outh + ((size_t)bhI * HDIM + e) * S_LEN + s0g;
            #pragma unroll
            for (int c = 0; c < 8; ++c) {
                ushort tmp[8];
                #pragma unroll
                for (int j = 0; j < 8; ++j)
                    tmp[j] = T[nloc * 130 + 2 * (c * 8 + j) + bsel];
                *(uint4*)(dst + c * 8) = *(uint4*)tmp;
            }
        }
        return;
    }

    #pragma unroll
    for (int j = 0; j < NJ; ++j) {
        const int n = n0 + nBase + j * 16 + cn;
        const float bv = bias[n];
        #pragma unroll
        for (int i = 0; i < MI; ++i) {
            const int mrow = m0 + mBase + i * 16 + quad * 4;
            #pragma unroll
            for (int g = 0; g < 4; ++g) {
                const float val = acc[i][j][g] + bv;
                const int m = mrow + g;
                if (MODE == 1) {
                    outf[(size_t)m * DMODEL + n] = val;
                } else {
                    const int l = m >> 11, rem = m & 2047;
                    const int s = rem >> 1, b = rem & 1;
                    const int h = n >> 6, e = n & 63;
                    const int bh = l * 32 + b * 16 + h;
                    const size_t idx = (((size_t)bh * S_LEN) + s) * HDIM + e;
                    if (MODE == 2) {
                        ushort hi, lov; split_bf16(val, hi, lov);
                        outh[idx] = hi;
                        outh[idx + 2097152] = lov;    // lo plane offset (Q only)
                    } else {   // MODE 4: hi only (K)
                        outh[idx] = bf16_rne(val);
                    }
                }
            }
        }
    }
}

// ---------------------------------------------------------------------------
// MFMA flash attention. Block = 4 waves, each wave owns q=64 (two 32-row
// A-frag sets sharing every K/V load). Grid = 512 flat, XCD-swizzled so all
// 4 q-blocks of a (bh,l) pair (and 16 pairs) co-locate on one XCD's L2.
// K/V are hi-plane only; Q keeps hi+lo in registers (loaded once).
//   A-frag (32x32x16): lane holds A[m=lid][k=half*8+j]
//   C/D:               col=lid, row=(reg&3)+8*(reg>>2)+4*half
// P stored bf16-hi in pad-36 ushort LDS (all accesses <=2-way, free).
// No-max softmax, linear row sums, one shuffle-reduce, atomicAdd epilogue.
// ---------------------------------------------------------------------------
__global__ __launch_bounds__(256, 2)
void attn_mfma(const ushort* __restrict__ qhg, const ushort* __restrict__ qlg,
               const ushort* __restrict__ kh, const ushort* __restrict__ vth,
               const float* __restrict__ lwraw, float* __restrict__ yb)
{
    __shared__ ushort Ps[8][32][36];   // [wave*2+u][key][q]  18,432 B

    const int t    = threadIdx.x;
    const int wv   = t >> 6, lane = t & 63;
    const int half = lane >> 5, lid = lane & 31;

    // XCD co-location: fid&7 = xcd (round-robin dispatch assumption)
    const int fid  = blockIdx.x;
    const int xcd  = fid & 7, slot = fid >> 3;
    const int pair = xcd * 16 + (slot >> 2);     // 16 (bh,l) pairs per XCD
    const int qt   = slot & 3;
    const int bh   = pair & 31, l = pair >> 5;
    const int qbase = qt * 256 + wv * 64;
    const float SCL = 0.125f * 1.44269504088896340736f;  // hd^-0.5 * log2(e)

    float wl;
    {
        float v[LP1], wm = -3.0e38f;
        #pragma unroll
        for (int i = 0; i < LP1; ++i) { v[i] = lwraw[i]; wm = fmaxf(wm, v[i]); }
        float ws = 0.f;
        #pragma unroll
        for (int i = 0; i < LP1; ++i) { v[i] = __expf(v[i] - wm); ws += v[i]; }
        wl = v[l] / ws;
    }

    // Q A-frags (hi+lo) for both q-sets, from pre-split planes
    bf16x8 qh[2][4], ql[2][4];
    #pragma unroll
    for (int u = 0; u < 2; ++u) {
        const size_t qoff = ((size_t)bh * S_LEN + qbase + u * 32 + lid) * HDIM + half * 8;
        #pragma unroll
        for (int es = 0; es < 4; ++es) {
            qh[u][es] = *(const bf16x8*)(qhg + qoff + es * 16);
            ql[u][es] = *(const bf16x8*)(qlg + qoff + es * 16);
        }
    }

    f32x16 o[2][2];
    #pragma unroll
    for (int u = 0; u < 2; ++u)
        #pragma unroll
        for (int d = 0; d < 2; ++d)
            #pragma unroll
            for (int i = 0; i < 16; ++i) o[u][d][i] = 0.f;
    float ls[2][16];
    #pragma unroll
    for (int u = 0; u < 2; ++u)
        #pragma unroll
        for (int i = 0; i < 16; ++i) ls[u][i] = 0.f;

    const size_t kvo = (size_t)(l * BHEADS + bh) * S_LEN * HDIM;

    for (int kt = 0; kt < 16; ++kt) {
        #pragma unroll
        for (int kc = 0; kc < 2; ++kc) {
            // ---- K frags (hi only), independent loads issued together ----
            bf16x8 kb[4];
            #pragma unroll
            for (int es = 0; es < 4; ++es)
                kb[es] = *(const bf16x8*)(kh + kvo
                          + (size_t)(kt * 64 + kc * 32 + lid) * HDIM + es * 16 + half * 8);

            // ---- S = (Qh + Ql) K^T for both q-sets ----
            f32x16 sa[2];
            #pragma unroll
            for (int u = 0; u < 2; ++u)
                #pragma unroll
                for (int i = 0; i < 16; ++i) sa[u][i] = 0.f;
            #pragma unroll
            for (int es = 0; es < 4; ++es)
                #pragma unroll
                for (int u = 0; u < 2; ++u) {
                    sa[u] = __builtin_amdgcn_mfma_f32_32x32x16_bf16(qh[u][es], kb[es], sa[u], 0, 0, 0);
                    sa[u] = __builtin_amdgcn_mfma_f32_32x32x16_bf16(ql[u][es], kb[es], sa[u], 0, 0, 0);
                }

            // ---- V frags (hi only) early, overlap P VALU ----
            bf16x8 vb[2][2];
            #pragma unroll
            for (int ks = 0; ks < 2; ++ks)
                #pragma unroll
                for (int dg = 0; dg < 2; ++dg)
                    vb[ks][dg] = *(const bf16x8*)(vth + kvo
                                  + (size_t)(dg * 32 + lid) * S_LEN
                                  + kt * 64 + kc * 32 + ks * 16 + half * 8);

            // ---- P = exp2(s*SCL), row sums, bf16-hi to LDS ----
            #pragma unroll
            for (int u = 0; u < 2; ++u) {
                ushort ph[16];
                #pragma unroll
                for (int r = 0; r < 16; ++r) {
                    const float p = exp2f(sa[u][r] * SCL);
                    ls[u][r] += p;
                    ph[r] = bf16_rne(p);
                }
                #pragma unroll
                for (int g = 0; g < 4; ++g)   // rows 4g..4g+3 -> q = 8g+4*half+rr
                    *(uint2*)&Ps[wv * 2 + u][lid][8 * g + 4 * half] = *(uint2*)&ph[4 * g];
            }

            // ---- O += P V ----
            #pragma unroll
            for (int ks = 0; ks < 2; ++ks)
                #pragma unroll
                for (int u = 0; u < 2; ++u) {
                    ushort pa[8];
                    #pragma unroll
                    for (int j = 0; j < 8; ++j)
                        pa[j] = Ps[wv * 2 + u][ks * 16 + half * 8 + j][lid];
                    const bf16x8 pf = *(bf16x8*)pa;
                    #pragma unroll
                    for (int dg = 0; dg < 2; ++dg)
                        o[u][dg] = __builtin_amdgcn_mfma_f32_32x32x16_bf16(pf, vb[ks][dg], o[u][dg], 0, 0, 0);
                }
        }
    }

    // ---- row-sum reduction across the 32 key-columns ----
    #pragma unroll
    for (int u = 0; u < 2; ++u)
        #pragma unroll
        for (int r = 0; r < 16; ++r) {
            float v = ls[u][r];
            #pragma unroll
            for (int off = 1; off < 32; off <<= 1) v += __shfl_xor(v, off, 32);
            ls[u][r] = v;
        }

    // ---- epilogue: atomicAdd w_l * O / ls into ybuf[s][b][d] ----
    const int b = bh >> 4, hh = bh & 15;
    #pragma unroll
    for (int u = 0; u < 2; ++u)
        #pragma unroll
        for (int r = 0; r < 16; ++r) {
            const int q = qbase + u * 32 + 8 * (r >> 2) + 4 * half + (r & 3);
            const float sc = wl / ls[u][r];
            #pragma unroll
            for (int dg = 0; dg < 2; ++dg) {
                const int d = hh * HDIM + dg * 32 + lid;
                atomicAdd(&yb[((size_t)q * BATCH + b) * DMODEL + d], o[u][dg][r] * sc);
            }
        }
}

// ---------------------------------------------------------------------------
extern "C" void kernel_launch(void* const* d_in, const int* in_sizes, int n_in,
                              void* d_out, int out_size, void* d_ws, size_t ws_size,
                              hipStream_t stream) {
    const float* x  = (const float*)d_in[0];
    const float* lo = (const float*)d_in[1];
    const float* Wq = (const float*)d_in[2];
    const float* bq = (const float*)d_in[3];
    const float* Wk = (const float*)d_in[4];
    const float* bk = (const float*)d_in[5];
    const float* Wv = (const float*)d_in[6];
    const float* bv = (const float*)d_in[7];
    const float* Wo = (const float*)d_in[8];
    const float* bo = (const float*)d_in[9];
    const float* lw = (const float*)d_in[10];
    float* out = (float*)d_out;

    char* ws = (char*)d_ws;
    ushort* XsH  = (ushort*)(ws);                          // 16,777,216 B
    ushort* WH   = (ushort*)(ws + 16777216);               //  8,388,608 B
    ushort* WL   = (ushort*)(ws + 25165824);               //  8,388,608 B
    ushort* qhb  = (ushort*)(ws + 33554432);               //  8,388,608 B (hi + lo planes)
    ushort* khb  = (ushort*)(ws + 41943040);               // 16,777,216 B
    ushort* vthb = (ushort*)(ws + 58720256);               // 16,777,216 B
    float*  ybuf = (float*)(ws + 75497472);                //  8,388,608 B
    // total 83,886,080 B

    hipMemsetAsync(ybuf, 0, (size_t)ROWS_PL * DMODEL * sizeof(float), stream);

    dim3 blk(256);
    // pre-split activations (hi) and weights (hi+lo)
    presplit<<<dim3(3072, 1, 6), blk, 0, stream>>>(x, lo, Wq, Wk, Wv, Wo, XsH, WH, WL);
    // Q projection -> hi+lo planes [b*16+h][s][e]   (M=2048, BM=64, 256 blocks)
    proj_bf16<2, 2, false><<<dim3(8, 32), blk, 0, stream>>>(XsH, nullptr, WH, WL, bq, nullptr, qhb);
    // K projection -> hi plane [l*32+b*16+h][s][e]  (M=8192, BM=128)
    proj_bf16<4, 4, false><<<dim3(8, 64), blk, 0, stream>>>(XsH, nullptr, WH + 1048576, WL + 1048576, bk, nullptr, khb);
    // V projection -> hi plane transposed [l*32+b*16+h][e][s]
    proj_bf16<4, 5, false><<<dim3(8, 64), blk, 0, stream>>>(XsH, nullptr, WH + 2097152, WL + 2097152, bv, nullptr, vthb);
    // attention: 512 XCD-swizzled blocks, 4 waves, wave = q64
    attn_mfma<<<dim3(512), blk, 0, stream>>>(qhb, qhb + 2097152, khb, vthb, lw, ybuf);
    // output projection (fp32 A rounded to bf16-hi during staging; BM=64, 256 blocks)
    proj_bf16<2, 1, true><<<dim3(8, 32), blk, 0, stream>>>(nullptr, ybuf, WH + 3145728, WL + 3145728, bo, out, nullptr);
}

// Round 7
// 378.656 us; speedup vs baseline: 2.1436x; 1.4672x over previous
//
#include <hip/hip_runtime.h>
#include <math.h>

// Problem constants (fixed by reference setup)
#define S_LEN   1024
#define BATCH   2
#define DMODEL  1024
#define NHEADS  16
#define HDIM    64
#define BHEADS  32          // BATCH*NHEADS
#define LP1     4           // 1 + L layers
#define ROWS_PL 2048        // S*B rows per layer

typedef __attribute__((ext_vector_type(8)))  short bf16x8;   // 8 bf16 = 4 VGPRs
typedef __attribute__((ext_vector_type(4)))  float f32x4;
typedef __attribute__((ext_vector_type(16))) float f32x16;

__device__ inline ushort bf16_rne(float a) {
    unsigned u = __float_as_uint(a);
    return (ushort)((u + 0x7FFFu + ((u >> 16) & 1u)) >> 16);
}
__device__ inline float bf16_up(ushort h) { return __uint_as_float(((unsigned)h) << 16); }
__device__ inline void split_bf16(float a, ushort &hi, ushort &lo) {
    hi = bf16_rne(a);
    lo = bf16_rne(a - bf16_up(hi));
}

// ---------------------------------------------------------------------------
// Pre-split WEIGHTS only -> hi+lo bf16 planes. 16 MB read, 16 MB write.
// ---------------------------------------------------------------------------
__global__ __launch_bounds__(256)
void presplit_w(const float* __restrict__ Wq, const float* __restrict__ Wk,
                const float* __restrict__ Wv, const float* __restrict__ Wo,
                ushort* __restrict__ WH, ushort* __restrict__ WL)
{
    const int z = blockIdx.y;
    const float* wsrc[4] = { Wq, Wk, Wv, Wo };
    const float* src = wsrc[z];
    ushort* dh = WH + (size_t)z * 1048576;
    ushort* dl = WL + (size_t)z * 1048576;
    const int i = (blockIdx.x * 256 + threadIdx.x) * 8;
    float v[8];
    *(float4*)&v[0] = *(const float4*)(src + i);
    *(float4*)&v[4] = *(const float4*)(src + i + 4);
    ushort h[8], l[8];
    #pragma unroll
    for (int j = 0; j < 8; ++j) { h[j] = bf16_rne(v[j]); l[j] = bf16_rne(v[j] - bf16_up(h[j])); }
    *(uint4*)(dh + i) = *(uint4*)h;
    *(uint4*)(dl + i) = *(uint4*)l;
}

// ---------------------------------------------------------------------------
// Q / O projection. C[2048,1024] = rne(A_f32) @ (W_hi+W_lo)^T + bias.
// BM=BN=64, BK=32, 256 thr (2x2 waves, 2x2 frags). LDS stride 40 (pad ->
// all frag b128 reads 2-way = free). Grid (16,32) = 512 blocks.
// MODE 0: split hi/lo planes at [b*16+h][s][e]  (Q; A = x)
// MODE 1: fp32 row-major out[m][n]              (O; A = ybuf)
// ---------------------------------------------------------------------------
template<int MODE>
__global__ __launch_bounds__(256)
void proj_qo(const float* __restrict__ Af,
             const ushort* __restrict__ Bhg, const ushort* __restrict__ Blg,
             const float* __restrict__ bias,
             float* __restrict__ outf, ushort* __restrict__ outh,
             ushort* __restrict__ outl)
{
    __shared__ ushort smem[3 * 2560];        // Ah, Bh, Bl: 64 rows x 40
    ushort* Ah = smem;
    ushort* Bh = smem + 2560;
    ushort* Bl = smem + 5120;

    const int t  = threadIdx.x;
    const int m0 = blockIdx.y * 64, n0 = blockIdx.x * 64;

    const float*  Ab  = Af  + (size_t)m0 * DMODEL;
    const ushort* Bbh = Bhg + (size_t)n0 * DMODEL;
    const ushort* Bbl = Blg + (size_t)n0 * DMODEL;

    const int wave = t >> 6, lane = t & 63;
    const int quad = lane >> 4, r = lane & 15;
    const int wm = wave & 1, wn = wave >> 1;
    const int mBase = wm * 32, nBase = wn * 32;

    const int arow = t >> 2, aoff = (t & 3) * 8;   // 8 elems/thread/plane

    f32x4 acc[2][2];
    #pragma unroll
    for (int i = 0; i < 2; ++i)
        #pragma unroll
        for (int j = 0; j < 2; ++j) acc[i][j] = (f32x4){0.f, 0.f, 0.f, 0.f};

    for (int k0 = 0; k0 < DMODEL; k0 += 32) {
        float fv[8];
        {
            const float* p = Ab + (size_t)arow * DMODEL + k0 + aoff;
            *(float4*)&fv[0] = *(const float4*)p;
            *(float4*)&fv[4] = *(const float4*)(p + 4);
        }
        uint4 bhv = *(const uint4*)(Bbh + (size_t)arow * DMODEL + k0 + aoff);
        uint4 blv = *(const uint4*)(Bbl + (size_t)arow * DMODEL + k0 + aoff);
        ushort hv[8];
        #pragma unroll
        for (int j = 0; j < 8; ++j) hv[j] = bf16_rne(fv[j]);
        __syncthreads();   // previous iteration's frag reads done
        *(uint4*)&Ah[arow * 40 + aoff] = *(uint4*)hv;
        *(uint4*)&Bh[arow * 40 + aoff] = bhv;
        *(uint4*)&Bl[arow * 40 + aoff] = blv;
        __syncthreads();
        bf16x8 fa[2], fbh[2], fbl[2];
        #pragma unroll
        for (int i = 0; i < 2; ++i)
            fa[i] = *(const bf16x8*)&Ah[(mBase + i * 16 + r) * 40 + quad * 8];
        #pragma unroll
        for (int j = 0; j < 2; ++j) {
            fbh[j] = *(const bf16x8*)&Bh[(nBase + j * 16 + r) * 40 + quad * 8];
            fbl[j] = *(const bf16x8*)&Bl[(nBase + j * 16 + r) * 40 + quad * 8];
        }
        #pragma unroll
        for (int i = 0; i < 2; ++i)
            #pragma unroll
            for (int j = 0; j < 2; ++j) {
                acc[i][j] = __builtin_amdgcn_mfma_f32_16x16x32_bf16(fa[i], fbh[j], acc[i][j], 0, 0, 0);
                acc[i][j] = __builtin_amdgcn_mfma_f32_16x16x32_bf16(fa[i], fbl[j], acc[i][j], 0, 0, 0);
            }
    }

    const int cn = lane & 15;
    #pragma unroll
    for (int j = 0; j < 2; ++j) {
        const int n = n0 + nBase + j * 16 + cn;
        const float bv = bias[n];
        #pragma unroll
        for (int i = 0; i < 2; ++i) {
            const int mrow = m0 + mBase + i * 16 + quad * 4;
            #pragma unroll
            for (int g = 0; g < 4; ++g) {
                const float val = acc[i][j][g] + bv;
                const int m = mrow + g;
                if (MODE == 1) {
                    outf[(size_t)m * DMODEL + n] = val;
                } else {
                    const int s = m >> 1, b = m & 1;
                    const int bh = b * 16 + (n >> 6), e = n & 63;
                    const size_t idx = (((size_t)bh * S_LEN) + s) * HDIM + e;
                    ushort hi, lov; split_bf16(val, hi, lov);
                    outh[idx] = hi; outl[idx] = lov;
                }
            }
        }
    }
}

// ---------------------------------------------------------------------------
// Fused K+V projection. A = rne([x ; layer_outputs]) staged ONCE; two GEMMs
// against Wk and Wv (hi+lo planes each). BM=64, BN=128, BK=32, 256 thr
// (2x2 waves; MI=2, NJ=4 per output). Grid (8,128) = 1024 blocks; fid&7=bx
// keeps each n-column's weight slice XCD-local.
// K epilogue: hi plane at [l*32+b*16+h][s][e]
// V epilogue: hi plane at [l*32+b*16+h][e][s] via LDS transpose, 64 B/thread
// coalesced stores.
// ---------------------------------------------------------------------------
__global__ __launch_bounds__(256)
void proj_kv(const float* __restrict__ x, const float* __restrict__ lo,
             const ushort* __restrict__ KWh, const ushort* __restrict__ KWl,
             const ushort* __restrict__ VWh, const ushort* __restrict__ VWl,
             const float* __restrict__ bk, const float* __restrict__ bv,
             ushort* __restrict__ kout, ushort* __restrict__ vout)
{
    // Ah 64x40 + 4 B-planes 128x40  = 23040 ushorts = 46 KB
    __shared__ ushort smem[2560 + 4 * 5120];
    ushort* Ah = smem;
    ushort* Kh = smem + 2560;
    ushort* Kl = Kh + 5120;
    ushort* Vh = Kl + 5120;
    ushort* Vl = Vh + 5120;

    const int t  = threadIdx.x;
    const int m0 = blockIdx.y * 64, n0 = blockIdx.x * 128;

    const int lyr = m0 >> 11;
    const float* src = (lyr == 0) ? x : (lo + (size_t)(lyr - 1) * ROWS_PL * DMODEL);
    const float* Ab  = src + (size_t)(m0 & 2047) * DMODEL;

    const ushort* KhB = KWh + (size_t)n0 * DMODEL;
    const ushort* KlB = KWl + (size_t)n0 * DMODEL;
    const ushort* VhB = VWh + (size_t)n0 * DMODEL;
    const ushort* VlB = VWl + (size_t)n0 * DMODEL;

    const int wave = t >> 6, lane = t & 63;
    const int quad = lane >> 4, r = lane & 15;
    const int wm = wave & 1, wn = wave >> 1;
    const int mBase = wm * 32, nBase = wn * 64;

    const int arow = t >> 2, aoff = (t & 3) * 8;   // A: 8 fp32/thread
    const int brow = t >> 1, boff = (t & 1) * 16;  // B: 16 u/thread/plane

    f32x4 aK[2][4], aV[2][4];
    #pragma unroll
    for (int i = 0; i < 2; ++i)
        #pragma unroll
        for (int j = 0; j < 4; ++j) {
            aK[i][j] = (f32x4){0.f, 0.f, 0.f, 0.f};
            aV[i][j] = (f32x4){0.f, 0.f, 0.f, 0.f};
        }

    for (int k0 = 0; k0 < DMODEL; k0 += 32) {
        float fv[8];
        {
            const float* p = Ab + (size_t)arow * DMODEL + k0 + aoff;
            *(float4*)&fv[0] = *(const float4*)p;
            *(float4*)&fv[4] = *(const float4*)(p + 4);
        }
        uint4 kh0, kh1, kl0, kl1, vh0, vh1, vl0, vl1;
        {
            const size_t bo = (size_t)brow * DMODEL + k0 + boff;
            kh0 = *(const uint4*)(KhB + bo); kh1 = *(const uint4*)(KhB + bo + 8);
            kl0 = *(const uint4*)(KlB + bo); kl1 = *(const uint4*)(KlB + bo + 8);
            vh0 = *(const uint4*)(VhB + bo); vh1 = *(const uint4*)(VhB + bo + 8);
            vl0 = *(const uint4*)(VlB + bo); vl1 = *(const uint4*)(VlB + bo + 8);
        }
        ushort hv[8];
        #pragma unroll
        for (int j = 0; j < 8; ++j) hv[j] = bf16_rne(fv[j]);
        __syncthreads();
        *(uint4*)&Ah[arow * 40 + aoff] = *(uint4*)hv;
        {
            ushort* d = &Kh[brow * 40 + boff];
            *(uint4*)d = kh0; *(uint4*)(d + 8) = kh1;
            d = &Kl[brow * 40 + boff];
            *(uint4*)d = kl0; *(uint4*)(d + 8) = kl1;
            d = &Vh[brow * 40 + boff];
            *(uint4*)d = vh0; *(uint4*)(d + 8) = vh1;
            d = &Vl[brow * 40 + boff];
            *(uint4*)d = vl0; *(uint4*)(d + 8) = vl1;
        }
        __syncthreads();
        bf16x8 fa[2];
        #pragma unroll
        for (int i = 0; i < 2; ++i)
            fa[i] = *(const bf16x8*)&Ah[(mBase + i * 16 + r) * 40 + quad * 8];
        #pragma unroll
        for (int j = 0; j < 4; ++j) {
            const int rowb = (nBase + j * 16 + r) * 40 + quad * 8;
            const bf16x8 fkh = *(const bf16x8*)&Kh[rowb];
            const bf16x8 fkl = *(const bf16x8*)&Kl[rowb];
            #pragma unroll
            for (int i = 0; i < 2; ++i) {
                aK[i][j] = __builtin_amdgcn_mfma_f32_16x16x32_bf16(fa[i], fkh, aK[i][j], 0, 0, 0);
                aK[i][j] = __builtin_amdgcn_mfma_f32_16x16x32_bf16(fa[i], fkl, aK[i][j], 0, 0, 0);
            }
            const bf16x8 fvh = *(const bf16x8*)&Vh[rowb];
            const bf16x8 fvl = *(const bf16x8*)&Vl[rowb];
            #pragma unroll
            for (int i = 0; i < 2; ++i) {
                aV[i][j] = __builtin_amdgcn_mfma_f32_16x16x32_bf16(fa[i], fvh, aV[i][j], 0, 0, 0);
                aV[i][j] = __builtin_amdgcn_mfma_f32_16x16x32_bf16(fa[i], fvl, aV[i][j], 0, 0, 0);
            }
        }
    }

    const int cn = lane & 15;

    // ---- K epilogue: hi plane, [l*32+b*16+h][s][e] ----
    #pragma unroll
    for (int j = 0; j < 4; ++j) {
        const int n = n0 + nBase + j * 16 + cn;
        const float bb = bk[n];
        #pragma unroll
        for (int i = 0; i < 2; ++i) {
            #pragma unroll
            for (int g = 0; g < 4; ++g) {
                const int m = m0 + mBase + i * 16 + quad * 4 + g;
                const int rem = m & 2047, s = rem >> 1, b = rem & 1;
                const int bh = lyr * 32 + b * 16 + (n >> 6);
                kout[(((size_t)bh * S_LEN) + s) * HDIM + (n & 63)] = bf16_rne(aK[i][j][g] + bb);
            }
        }
    }

    // ---- V epilogue: transpose via LDS, coalesced stores ----
    ushort* T = smem;   // [128][66]
    __syncthreads();    // K-loop frag reads done
    #pragma unroll
    for (int j = 0; j < 4; ++j) {
        const int nloc = nBase + j * 16 + cn;
        const float bb = bv[n0 + nloc];
        #pragma unroll
        for (int i = 0; i < 2; ++i) {
            #pragma unroll
            for (int g = 0; g < 4; ++g) {
                const int mloc = mBase + i * 16 + quad * 4 + g;
                T[nloc * 66 + mloc] = bf16_rne(aV[i][j][g] + bb);
            }
        }
    }
    __syncthreads();
    {
        const int nloc = t >> 1, bsel = t & 1;
        const int n = n0 + nloc, h = n >> 6, e = n & 63;
        const int s0g = (m0 & 2047) >> 1;           // 32 s-values per block
        const int bhI = lyr * 32 + bsel * 16 + h;
        ushort* dst = vout + ((size_t)bhI * HDIM + e) * S_LEN + s0g;
        #pragma unroll
        for (int c = 0; c < 4; ++c) {
            ushort tmp[8];
            #pragma unroll
            for (int j = 0; j < 8; ++j)
                tmp[j] = T[nloc * 66 + 2 * (c * 8 + j) + bsel];
            *(uint4*)(dst + c * 8) = *(uint4*)tmp;
        }
    }
}

// ---------------------------------------------------------------------------
// MFMA flash attention (unchanged from R6 — verified fast). Block = 4 waves,
// wave owns q=64 (two 32-row A-frag sets sharing all K/V loads). Grid 512
// flat, XCD-swizzled: all 4 q-blocks of a (bh,l) pair co-locate on one XCD.
// K/V hi-plane only; Q hi+lo in registers. No-max softmax, linear row sums,
// one shuffle-reduce, atomicAdd epilogue into ybuf[s][b][d].
// ---------------------------------------------------------------------------
__global__ __launch_bounds__(256, 2)
void attn_mfma(const ushort* __restrict__ qhg, const ushort* __restrict__ qlg,
               const ushort* __restrict__ kh, const ushort* __restrict__ vth,
               const float* __restrict__ lwraw, float* __restrict__ yb)
{
    __shared__ ushort Ps[8][32][36];   // [wave*2+u][key][q]  18,432 B

    const int t    = threadIdx.x;
    const int wv   = t >> 6, lane = t & 63;
    const int half = lane >> 5, lid = lane & 31;

    const int fid  = blockIdx.x;
    const int xcd  = fid & 7, slot = fid >> 3;
    const int pair = xcd * 16 + (slot >> 2);     // 16 (bh,l) pairs per XCD
    const int qt   = slot & 3;
    const int bh   = pair & 31, l = pair >> 5;
    const int qbase = qt * 256 + wv * 64;
    const float SCL = 0.125f * 1.44269504088896340736f;  // hd^-0.5 * log2(e)

    float wl;
    {
        float v[LP1], wm = -3.0e38f;
        #pragma unroll
        for (int i = 0; i < LP1; ++i) { v[i] = lwraw[i]; wm = fmaxf(wm, v[i]); }
        float ws = 0.f;
        #pragma unroll
        for (int i = 0; i < LP1; ++i) { v[i] = __expf(v[i] - wm); ws += v[i]; }
        wl = v[l] / ws;
    }

    bf16x8 qh[2][4], ql[2][4];
    #pragma unroll
    for (int u = 0; u < 2; ++u) {
        const size_t qoff = ((size_t)bh * S_LEN + qbase + u * 32 + lid) * HDIM + half * 8;
        #pragma unroll
        for (int es = 0; es < 4; ++es) {
            qh[u][es] = *(const bf16x8*)(qhg + qoff + es * 16);
            ql[u][es] = *(const bf16x8*)(qlg + qoff + es * 16);
        }
    }

    f32x16 o[2][2];
    #pragma unroll
    for (int u = 0; u < 2; ++u)
        #pragma unroll
        for (int d = 0; d < 2; ++d)
            #pragma unroll
            for (int i = 0; i < 16; ++i) o[u][d][i] = 0.f;
    float ls[2][16];
    #pragma unroll
    for (int u = 0; u < 2; ++u)
        #pragma unroll
        for (int i = 0; i < 16; ++i) ls[u][i] = 0.f;

    const size_t kvo = (size_t)(l * BHEADS + bh) * S_LEN * HDIM;

    for (int kt = 0; kt < 16; ++kt) {
        #pragma unroll
        for (int kc = 0; kc < 2; ++kc) {
            bf16x8 kb[4];
            #pragma unroll
            for (int es = 0; es < 4; ++es)
                kb[es] = *(const bf16x8*)(kh + kvo
                          + (size_t)(kt * 64 + kc * 32 + lid) * HDIM + es * 16 + half * 8);

            f32x16 sa[2];
            #pragma unroll
            for (int u = 0; u < 2; ++u)
                #pragma unroll
                for (int i = 0; i < 16; ++i) sa[u][i] = 0.f;
            #pragma unroll
            for (int es = 0; es < 4; ++es)
                #pragma unroll
                for (int u = 0; u < 2; ++u) {
                    sa[u] = __builtin_amdgcn_mfma_f32_32x32x16_bf16(qh[u][es], kb[es], sa[u], 0, 0, 0);
                    sa[u] = __builtin_amdgcn_mfma_f32_32x32x16_bf16(ql[u][es], kb[es], sa[u], 0, 0, 0);
                }

            bf16x8 vb[2][2];
            #pragma unroll
            for (int ks = 0; ks < 2; ++ks)
                #pragma unroll
                for (int dg = 0; dg < 2; ++dg)
                    vb[ks][dg] = *(const bf16x8*)(vth + kvo
                                  + (size_t)(dg * 32 + lid) * S_LEN
                                  + kt * 64 + kc * 32 + ks * 16 + half * 8);

            #pragma unroll
            for (int u = 0; u < 2; ++u) {
                ushort ph[16];
                #pragma unroll
                for (int rr = 0; rr < 16; ++rr) {
                    const float p = exp2f(sa[u][rr] * SCL);
                    ls[u][rr] += p;
                    ph[rr] = bf16_rne(p);
                }
                #pragma unroll
                for (int g = 0; g < 4; ++g)
                    *(uint2*)&Ps[wv * 2 + u][lid][8 * g + 4 * half] = *(uint2*)&ph[4 * g];
            }

            #pragma unroll
            for (int ks = 0; ks < 2; ++ks)
                #pragma unroll
                for (int u = 0; u < 2; ++u) {
                    ushort pa[8];
                    #pragma unroll
                    for (int j = 0; j < 8; ++j)
                        pa[j] = Ps[wv * 2 + u][ks * 16 + half * 8 + j][lid];
                    const bf16x8 pf = *(bf16x8*)pa;
                    #pragma unroll
                    for (int dg = 0; dg < 2; ++dg)
                        o[u][dg] = __builtin_amdgcn_mfma_f32_32x32x16_bf16(pf, vb[ks][dg], o[u][dg], 0, 0, 0);
                }
        }
    }

    #pragma unroll
    for (int u = 0; u < 2; ++u)
        #pragma unroll
        for (int rr = 0; rr < 16; ++rr) {
            float v = ls[u][rr];
            #pragma unroll
            for (int off = 1; off < 32; off <<= 1) v += __shfl_xor(v, off, 32);
            ls[u][rr] = v;
        }

    const int b = bh >> 4, hh = bh & 15;
    #pragma unroll
    for (int u = 0; u < 2; ++u)
        #pragma unroll
        for (int rr = 0; rr < 16; ++rr) {
            const int q = qbase + u * 32 + 8 * (rr >> 2) + 4 * half + (rr & 3);
            const float sc = wl / ls[u][rr];
            #pragma unroll
            for (int dg = 0; dg < 2; ++dg) {
                const int d = hh * HDIM + dg * 32 + lid;
                atomicAdd(&yb[((size_t)q * BATCH + b) * DMODEL + d], o[u][dg][rr] * sc);
            }
        }
}

// ---------------------------------------------------------------------------
extern "C" void kernel_launch(void* const* d_in, const int* in_sizes, int n_in,
                              void* d_out, int out_size, void* d_ws, size_t ws_size,
                              hipStream_t stream) {
    const float* x  = (const float*)d_in[0];
    const float* lo = (const float*)d_in[1];
    const float* Wq = (const float*)d_in[2];
    const float* bq = (const float*)d_in[3];
    const float* Wk = (const float*)d_in[4];
    const float* bk = (const float*)d_in[5];
    const float* Wv = (const float*)d_in[6];
    const float* bv = (const float*)d_in[7];
    const float* Wo = (const float*)d_in[8];
    const float* bo = (const float*)d_in[9];
    const float* lw = (const float*)d_in[10];
    float* out = (float*)d_out;

    char* ws = (char*)d_ws;
    ushort* WH   = (ushort*)(ws);                          //  8,388,608 B
    ushort* WL   = (ushort*)(ws + 8388608);                //  8,388,608 B
    ushort* qhb  = (ushort*)(ws + 16777216);               //  4,194,304 B
    ushort* qlb  = (ushort*)(ws + 20971520);               //  4,194,304 B
    ushort* khb  = (ushort*)(ws + 25165824);               // 16,777,216 B
    ushort* vthb = (ushort*)(ws + 41943040);               // 16,777,216 B
    float*  ybuf = (float*)(ws + 58720256);                //  8,388,608 B
    // total 67,108,864 B

    hipMemsetAsync(ybuf, 0, (size_t)ROWS_PL * DMODEL * sizeof(float), stream);

    dim3 blk(256);
    // weights -> hi+lo planes
    presplit_w<<<dim3(512, 4), blk, 0, stream>>>(Wq, Wk, Wv, Wo, WH, WL);
    // Q projection -> hi/lo planes [b*16+h][s][e]
    proj_qo<0><<<dim3(16, 32), blk, 0, stream>>>(x, WH, WL, bq, nullptr, qhb, qlb);
    // fused K+V projection (K hi plane [bh][s][e]; V^T hi plane [bh][e][s])
    proj_kv<<<dim3(8, 128), blk, 0, stream>>>(x, lo,
        WH + 1048576, WL + 1048576, WH + 2097152, WL + 2097152,
        bk, bv, khb, vthb);
    // attention: 512 XCD-swizzled blocks, 4 waves, wave = q64
    attn_mfma<<<dim3(512), blk, 0, stream>>>(qhb, qlb, khb, vthb, lw, ybuf);
    // output projection
    proj_qo<1><<<dim3(16, 32), blk, 0, stream>>>(ybuf, WH + 3145728, WL + 3145728, bo, out, nullptr, nullptr);
}

// Round 8
// 345.609 us; speedup vs baseline: 2.3486x; 1.0956x over previous
//
#include <hip/hip_runtime.h>
#include <math.h>

// Problem constants (fixed by reference setup)
#define S_LEN   1024
#define BATCH   2
#define DMODEL  1024
#define NHEADS  16
#define HDIM    64
#define BHEADS  32          // BATCH*NHEADS
#define LP1     4           // 1 + L layers
#define ROWS_PL 2048        // S*B rows per layer

typedef __attribute__((ext_vector_type(8)))  short bf16x8;   // 8 bf16 = 4 VGPRs
typedef __attribute__((ext_vector_type(4)))  float f32x4;
typedef __attribute__((ext_vector_type(16))) float f32x16;

__device__ inline ushort bf16_rne(float a) {
    unsigned u = __float_as_uint(a);
    return (ushort)((u + 0x7FFFu + ((u >> 16) & 1u)) >> 16);
}
__device__ inline float bf16_up(ushort h) { return __uint_as_float(((unsigned)h) << 16); }
__device__ inline void split_bf16(float a, ushort &hi, ushort &lo) {
    hi = bf16_rne(a);
    lo = bf16_rne(a - bf16_up(hi));
}

// Async global->LDS, 16 B per lane. HW places lane i at lds_base + i*16.
__device__ inline void glds16(const ushort* g, ushort* l) {
    __builtin_amdgcn_global_load_lds(
        (const __attribute__((address_space(1))) void*)g,
        (__attribute__((address_space(3))) void*)l, 16, 0, 0);
}

// ---------------------------------------------------------------------------
// One-shot pre-split: Xs = [x ; layer_outputs] -> hi bf16 plane (for the
// glds-staged K/V GEMM); weights -> hi+lo planes. z-demuxed single launch.
// ---------------------------------------------------------------------------
__global__ __launch_bounds__(256)
void presplit(const float* __restrict__ x, const float* __restrict__ lo,
              const float* __restrict__ Wq, const float* __restrict__ Wk,
              const float* __restrict__ Wv, const float* __restrict__ Wo,
              ushort* __restrict__ XsH, ushort* __restrict__ WH,
              ushort* __restrict__ WL)
{
    const int z = blockIdx.z;
    const float* src; ushort* dh; ushort* dl = nullptr; int n;
    if (z == 0)      { src = x;  dh = XsH;           n = 2097152; }
    else if (z == 1) { src = lo; dh = XsH + 2097152; n = 6291456; }
    else {
        const float* wsrc[4] = { Wq, Wk, Wv, Wo };
        src = wsrc[z - 2];
        dh = WH + (size_t)(z - 2) * 1048576;
        dl = WL + (size_t)(z - 2) * 1048576;
        n = 1048576;
    }
    const int i = (blockIdx.x * 256 + threadIdx.x) * 8;
    if (i >= n) return;
    float v[8];
    *(float4*)&v[0] = *(const float4*)(src + i);
    *(float4*)&v[4] = *(const float4*)(src + i + 4);
    ushort h[8];
    #pragma unroll
    for (int j = 0; j < 8; ++j) h[j] = bf16_rne(v[j]);
    *(uint4*)(dh + i) = *(uint4*)h;
    if (dl) {
        ushort l[8];
        #pragma unroll
        for (int j = 0; j < 8; ++j) l[j] = bf16_rne(v[j] - bf16_up(h[j]));
        *(uint4*)(dl + i) = *(uint4*)l;
    }
}

// ---------------------------------------------------------------------------
// Q / O projection (unchanged from R7). C[2048,1024] = rne(A_f32) @
// (W_hi+W_lo)^T + bias. BM=BN=64, BK=32, 256 thr, LDS stride 40.
// MODE 0: split hi/lo planes at [b*16+h][s][e]  (Q; A = x)
// MODE 1: fp32 row-major out[m][n]              (O; A = ybuf)
// ---------------------------------------------------------------------------
template<int MODE>
__global__ __launch_bounds__(256)
void proj_qo(const float* __restrict__ Af,
             const ushort* __restrict__ Bhg, const ushort* __restrict__ Blg,
             const float* __restrict__ bias,
             float* __restrict__ outf, ushort* __restrict__ outh,
             ushort* __restrict__ outl)
{
    __shared__ ushort smem[3 * 2560];        // Ah, Bh, Bl: 64 rows x 40
    ushort* Ah = smem;
    ushort* Bh = smem + 2560;
    ushort* Bl = smem + 5120;

    const int t  = threadIdx.x;
    const int m0 = blockIdx.y * 64, n0 = blockIdx.x * 64;

    const float*  Ab  = Af  + (size_t)m0 * DMODEL;
    const ushort* Bbh = Bhg + (size_t)n0 * DMODEL;
    const ushort* Bbl = Blg + (size_t)n0 * DMODEL;

    const int wave = t >> 6, lane = t & 63;
    const int quad = lane >> 4, r = lane & 15;
    const int wm = wave & 1, wn = wave >> 1;
    const int mBase = wm * 32, nBase = wn * 32;

    const int arow = t >> 2, aoff = (t & 3) * 8;

    f32x4 acc[2][2];
    #pragma unroll
    for (int i = 0; i < 2; ++i)
        #pragma unroll
        for (int j = 0; j < 2; ++j) acc[i][j] = (f32x4){0.f, 0.f, 0.f, 0.f};

    for (int k0 = 0; k0 < DMODEL; k0 += 32) {
        float fv[8];
        {
            const float* p = Ab + (size_t)arow * DMODEL + k0 + aoff;
            *(float4*)&fv[0] = *(const float4*)p;
            *(float4*)&fv[4] = *(const float4*)(p + 4);
        }
        uint4 bhv = *(const uint4*)(Bbh + (size_t)arow * DMODEL + k0 + aoff);
        uint4 blv = *(const uint4*)(Bbl + (size_t)arow * DMODEL + k0 + aoff);
        ushort hv[8];
        #pragma unroll
        for (int j = 0; j < 8; ++j) hv[j] = bf16_rne(fv[j]);
        __syncthreads();
        *(uint4*)&Ah[arow * 40 + aoff] = *(uint4*)hv;
        *(uint4*)&Bh[arow * 40 + aoff] = bhv;
        *(uint4*)&Bl[arow * 40 + aoff] = blv;
        __syncthreads();
        bf16x8 fa[2], fbh[2], fbl[2];
        #pragma unroll
        for (int i = 0; i < 2; ++i)
            fa[i] = *(const bf16x8*)&Ah[(mBase + i * 16 + r) * 40 + quad * 8];
        #pragma unroll
        for (int j = 0; j < 2; ++j) {
            fbh[j] = *(const bf16x8*)&Bh[(nBase + j * 16 + r) * 40 + quad * 8];
            fbl[j] = *(const bf16x8*)&Bl[(nBase + j * 16 + r) * 40 + quad * 8];
        }
        #pragma unroll
        for (int i = 0; i < 2; ++i)
            #pragma unroll
            for (int j = 0; j < 2; ++j) {
                acc[i][j] = __builtin_amdgcn_mfma_f32_16x16x32_bf16(fa[i], fbh[j], acc[i][j], 0, 0, 0);
                acc[i][j] = __builtin_amdgcn_mfma_f32_16x16x32_bf16(fa[i], fbl[j], acc[i][j], 0, 0, 0);
            }
    }

    const int cn = lane & 15;
    #pragma unroll
    for (int j = 0; j < 2; ++j) {
        const int n = n0 + nBase + j * 16 + cn;
        const float bv = bias[n];
        #pragma unroll
        for (int i = 0; i < 2; ++i) {
            const int mrow = m0 + mBase + i * 16 + quad * 4;
            #pragma unroll
            for (int g = 0; g < 4; ++g) {
                const float val = acc[i][j][g] + bv;
                const int m = mrow + g;
                if (MODE == 1) {
                    outf[(size_t)m * DMODEL + n] = val;
                } else {
                    const int s = m >> 1, b = m & 1;
                    const int bh = b * 16 + (n >> 6), e = n & 63;
                    const size_t idx = (((size_t)bh * S_LEN) + s) * HDIM + e;
                    ushort hi, lov; split_bf16(val, hi, lov);
                    outh[idx] = hi; outl[idx] = lov;
                }
            }
        }
    }
}

// ---------------------------------------------------------------------------
// Fused K+V projection, m97-style glds staging. A = XsH (bf16 hi, pre-split)
// and 4 weight planes staged via __builtin_amdgcn_global_load_lds width=16 —
// no ds_writes, no conversion VALU in the K-loop. BM=64, BN=128, BK=32,
// 256 thr (2x2 waves). LDS 36 KB single-buffered (4 blocks/CU). Grid (8,128),
// fid&7 = bx keeps each n-column's weight slice XCD-local.
// K epilogue: hi plane at [l*32+b*16+h][s][e]
// V epilogue: hi plane at [l*32+b*16+h][e][s] via LDS transpose.
// ---------------------------------------------------------------------------
__global__ __launch_bounds__(256, 4)
void proj_kv(const ushort* __restrict__ XsH,
             const ushort* __restrict__ KWh, const ushort* __restrict__ KWl,
             const ushort* __restrict__ VWh, const ushort* __restrict__ VWl,
             const float* __restrict__ bk, const float* __restrict__ bv,
             ushort* __restrict__ kout, ushort* __restrict__ vout)
{
    __shared__ ushort smem[18432];       // Ah 64x32 + 4 planes 128x32 = 36 KB
    ushort* Ah = smem;                   // [64][32]
    ushort* Bp = smem + 2048;            // [plane][128][32]

    const int t  = threadIdx.x;
    const int m0 = blockIdx.y * 64, n0 = blockIdx.x * 128;
    const int lyr = m0 >> 11;

    const int wv = t >> 6, lane = t & 63;
    const int quad = lane >> 4, r = lane & 15;
    const int wm = wv & 1, wn = wv >> 1;
    const int mBase = wm * 32, nBase = wn * 64;

    // glds issue geometry: lane i covers (row = base + i>>2, kchunk = i&3)
    const int lrow = lane >> 2, lch = (lane & 3) * 8;

    const ushort* Asrc = XsH + (size_t)(m0 + wv * 16 + lrow) * DMODEL + lch;
    const ushort* Bw[4] = { KWh, KWl, VWh, VWl };
    const ushort* Bsrc[4][2];
    #pragma unroll
    for (int p = 0; p < 4; ++p)
        #pragma unroll
        for (int seg = 0; seg < 2; ++seg)
            Bsrc[p][seg] = Bw[p] + (size_t)(n0 + wv * 32 + seg * 16 + lrow) * DMODEL + lch;

    f32x4 aK[2][4], aV[2][4];
    #pragma unroll
    for (int i = 0; i < 2; ++i)
        #pragma unroll
        for (int j = 0; j < 4; ++j) {
            aK[i][j] = (f32x4){0.f, 0.f, 0.f, 0.f};
            aV[i][j] = (f32x4){0.f, 0.f, 0.f, 0.f};
        }

    for (int k0 = 0; k0 < DMODEL; k0 += 32) {
        // ---- async staging: 9 glds issues per wave ----
        glds16(Asrc + k0, Ah + (wv * 16) * 32);
        #pragma unroll
        for (int p = 0; p < 4; ++p)
            #pragma unroll
            for (int seg = 0; seg < 2; ++seg)
                glds16(Bsrc[p][seg] + k0,
                       Bp + p * 4096 + (wv * 32 + seg * 16) * 32);
        __syncthreads();   // drains vmcnt -> staged data visible

        // ---- fragments + MFMA ----
        bf16x8 fa[2];
        #pragma unroll
        for (int i = 0; i < 2; ++i)
            fa[i] = *(const bf16x8*)&Ah[(mBase + i * 16 + r) * 32 + quad * 8];
        #pragma unroll
        for (int j = 0; j < 4; ++j) {
            const int rowb = (nBase + j * 16 + r) * 32 + quad * 8;
            const bf16x8 fkh = *(const bf16x8*)&Bp[rowb];
            const bf16x8 fkl = *(const bf16x8*)&Bp[4096 + rowb];
            #pragma unroll
            for (int i = 0; i < 2; ++i) {
                aK[i][j] = __builtin_amdgcn_mfma_f32_16x16x32_bf16(fa[i], fkh, aK[i][j], 0, 0, 0);
                aK[i][j] = __builtin_amdgcn_mfma_f32_16x16x32_bf16(fa[i], fkl, aK[i][j], 0, 0, 0);
            }
            const bf16x8 fvh = *(const bf16x8*)&Bp[8192 + rowb];
            const bf16x8 fvl = *(const bf16x8*)&Bp[12288 + rowb];
            #pragma unroll
            for (int i = 0; i < 2; ++i) {
                aV[i][j] = __builtin_amdgcn_mfma_f32_16x16x32_bf16(fa[i], fvh, aV[i][j], 0, 0, 0);
                aV[i][j] = __builtin_amdgcn_mfma_f32_16x16x32_bf16(fa[i], fvl, aV[i][j], 0, 0, 0);
            }
        }
        __syncthreads();   // LDS consumed before next iteration's glds
    }

    const int cn = lane & 15;

    // ---- K epilogue: hi plane, [l*32+b*16+h][s][e] ----
    #pragma unroll
    for (int j = 0; j < 4; ++j) {
        const int n = n0 + nBase + j * 16 + cn;
        const float bb = bk[n];
        #pragma unroll
        for (int i = 0; i < 2; ++i) {
            #pragma unroll
            for (int g = 0; g < 4; ++g) {
                const int m = m0 + mBase + i * 16 + quad * 4 + g;
                const int rem = m & 2047, s = rem >> 1, b = rem & 1;
                const int bh = lyr * 32 + b * 16 + (n >> 6);
                kout[(((size_t)bh * S_LEN) + s) * HDIM + (n & 63)] = bf16_rne(aK[i][j][g] + bb);
            }
        }
    }

    // ---- V epilogue: transpose via LDS, coalesced stores ----
    ushort* T = smem;   // [128][66]
    #pragma unroll
    for (int j = 0; j < 4; ++j) {
        const int nloc = nBase + j * 16 + cn;
        const float bb = bv[n0 + nloc];
        #pragma unroll
        for (int i = 0; i < 2; ++i) {
            #pragma unroll
            for (int g = 0; g < 4; ++g) {
                const int mloc = mBase + i * 16 + quad * 4 + g;
                T[nloc * 66 + mloc] = bf16_rne(aV[i][j][g] + bb);
            }
        }
    }
    __syncthreads();
    {
        const int nloc = t >> 1, bsel = t & 1;
        const int n = n0 + nloc, h = n >> 6, e = n & 63;
        const int s0g = (m0 & 2047) >> 1;           // 32 s-values per block
        const int bhI = lyr * 32 + bsel * 16 + h;
        ushort* dst = vout + ((size_t)bhI * HDIM + e) * S_LEN + s0g;
        #pragma unroll
        for (int c = 0; c < 4; ++c) {
            ushort tmp[8];
            #pragma unroll
            for (int j = 0; j < 8; ++j)
                tmp[j] = T[nloc * 66 + 2 * (c * 8 + j) + bsel];
            *(uint4*)(dst + c * 8) = *(uint4*)tmp;
        }
    }
}

// ---------------------------------------------------------------------------
// MFMA flash attention (unchanged from R6/R7 — verified fast). Block = 4
// waves, wave owns q=64. Grid 512 flat, XCD-swizzled. K/V hi-plane only;
// Q hi+lo in registers. No-max softmax, linear row sums, one shuffle-reduce,
// atomicAdd epilogue into ybuf[s][b][d].
// ---------------------------------------------------------------------------
__global__ __launch_bounds__(256, 2)
void attn_mfma(const ushort* __restrict__ qhg, const ushort* __restrict__ qlg,
               const ushort* __restrict__ kh, const ushort* __restrict__ vth,
               const float* __restrict__ lwraw, float* __restrict__ yb)
{
    __shared__ ushort Ps[8][32][36];   // [wave*2+u][key][q]  18,432 B

    const int t    = threadIdx.x;
    const int wv   = t >> 6, lane = t & 63;
    const int half = lane >> 5, lid = lane & 31;

    const int fid  = blockIdx.x;
    const int xcd  = fid & 7, slot = fid >> 3;
    const int pair = xcd * 16 + (slot >> 2);     // 16 (bh,l) pairs per XCD
    const int qt   = slot & 3;
    const int bh   = pair & 31, l = pair >> 5;
    const int qbase = qt * 256 + wv * 64;
    const float SCL = 0.125f * 1.44269504088896340736f;  // hd^-0.5 * log2(e)

    float wl;
    {
        float v[LP1], wm = -3.0e38f;
        #pragma unroll
        for (int i = 0; i < LP1; ++i) { v[i] = lwraw[i]; wm = fmaxf(wm, v[i]); }
        float ws = 0.f;
        #pragma unroll
        for (int i = 0; i < LP1; ++i) { v[i] = __expf(v[i] - wm); ws += v[i]; }
        wl = v[l] / ws;
    }

    bf16x8 qh[2][4], ql[2][4];
    #pragma unroll
    for (int u = 0; u < 2; ++u) {
        const size_t qoff = ((size_t)bh * S_LEN + qbase + u * 32 + lid) * HDIM + half * 8;
        #pragma unroll
        for (int es = 0; es < 4; ++es) {
            qh[u][es] = *(const bf16x8*)(qhg + qoff + es * 16);
            ql[u][es] = *(const bf16x8*)(qlg + qoff + es * 16);
        }
    }

    f32x16 o[2][2];
    #pragma unroll
    for (int u = 0; u < 2; ++u)
        #pragma unroll
        for (int d = 0; d < 2; ++d)
            #pragma unroll
            for (int i = 0; i < 16; ++i) o[u][d][i] = 0.f;
    float ls[2][16];
    #pragma unroll
    for (int u = 0; u < 2; ++u)
        #pragma unroll
        for (int i = 0; i < 16; ++i) ls[u][i] = 0.f;

    const size_t kvo = (size_t)(l * BHEADS + bh) * S_LEN * HDIM;

    for (int kt = 0; kt < 16; ++kt) {
        #pragma unroll
        for (int kc = 0; kc < 2; ++kc) {
            bf16x8 kb[4];
            #pragma unroll
            for (int es = 0; es < 4; ++es)
                kb[es] = *(const bf16x8*)(kh + kvo
                          + (size_t)(kt * 64 + kc * 32 + lid) * HDIM + es * 16 + half * 8);

            f32x16 sa[2];
            #pragma unroll
            for (int u = 0; u < 2; ++u)
                #pragma unroll
                for (int i = 0; i < 16; ++i) sa[u][i] = 0.f;
            #pragma unroll
            for (int es = 0; es < 4; ++es)
                #pragma unroll
                for (int u = 0; u < 2; ++u) {
                    sa[u] = __builtin_amdgcn_mfma_f32_32x32x16_bf16(qh[u][es], kb[es], sa[u], 0, 0, 0);
                    sa[u] = __builtin_amdgcn_mfma_f32_32x32x16_bf16(ql[u][es], kb[es], sa[u], 0, 0, 0);
                }

            bf16x8 vb[2][2];
            #pragma unroll
            for (int ks = 0; ks < 2; ++ks)
                #pragma unroll
                for (int dg = 0; dg < 2; ++dg)
                    vb[ks][dg] = *(const bf16x8*)(vth + kvo
                                  + (size_t)(dg * 32 + lid) * S_LEN
                                  + kt * 64 + kc * 32 + ks * 16 + half * 8);

            #pragma unroll
            for (int u = 0; u < 2; ++u) {
                ushort ph[16];
                #pragma unroll
                for (int rr = 0; rr < 16; ++rr) {
                    const float p = exp2f(sa[u][rr] * SCL);
                    ls[u][rr] += p;
                    ph[rr] = bf16_rne(p);
                }
                #pragma unroll
                for (int g = 0; g < 4; ++g)
                    *(uint2*)&Ps[wv * 2 + u][lid][8 * g + 4 * half] = *(uint2*)&ph[4 * g];
            }

            #pragma unroll
            for (int ks = 0; ks < 2; ++ks)
                #pragma unroll
                for (int u = 0; u < 2; ++u) {
                    ushort pa[8];
                    #pragma unroll
                    for (int j = 0; j < 8; ++j)
                        pa[j] = Ps[wv * 2 + u][ks * 16 + half * 8 + j][lid];
                    const bf16x8 pf = *(bf16x8*)pa;
                    #pragma unroll
                    for (int dg = 0; dg < 2; ++dg)
                        o[u][dg] = __builtin_amdgcn_mfma_f32_32x32x16_bf16(pf, vb[ks][dg], o[u][dg], 0, 0, 0);
                }
        }
    }

    #pragma unroll
    for (int u = 0; u < 2; ++u)
        #pragma unroll
        for (int rr = 0; rr < 16; ++rr) {
            float v = ls[u][rr];
            #pragma unroll
            for (int off = 1; off < 32; off <<= 1) v += __shfl_xor(v, off, 32);
            ls[u][rr] = v;
        }

    const int b = bh >> 4, hh = bh & 15;
    #pragma unroll
    for (int u = 0; u < 2; ++u)
        #pragma unroll
        for (int rr = 0; rr < 16; ++rr) {
            const int q = qbase + u * 32 + 8 * (rr >> 2) + 4 * half + (rr & 3);
            const float sc = wl / ls[u][rr];
            #pragma unroll
            for (int dg = 0; dg < 2; ++dg) {
                const int d = hh * HDIM + dg * 32 + lid;
                atomicAdd(&yb[((size_t)q * BATCH + b) * DMODEL + d], o[u][dg][rr] * sc);
            }
        }
}

// ---------------------------------------------------------------------------
extern "C" void kernel_launch(void* const* d_in, const int* in_sizes, int n_in,
                              void* d_out, int out_size, void* d_ws, size_t ws_size,
                              hipStream_t stream) {
    const float* x  = (const float*)d_in[0];
    const float* lo = (const float*)d_in[1];
    const float* Wq = (const float*)d_in[2];
    const float* bq = (const float*)d_in[3];
    const float* Wk = (const float*)d_in[4];
    const float* bk = (const float*)d_in[5];
    const float* Wv = (const float*)d_in[6];
    const float* bv = (const float*)d_in[7];
    const float* Wo = (const float*)d_in[8];
    const float* bo = (const float*)d_in[9];
    const float* lw = (const float*)d_in[10];
    float* out = (float*)d_out;

    char* ws = (char*)d_ws;
    ushort* XsH  = (ushort*)(ws);                          // 16,777,216 B
    ushort* WH   = (ushort*)(ws + 16777216);               //  8,388,608 B
    ushort* WL   = (ushort*)(ws + 25165824);               //  8,388,608 B
    ushort* qhb  = (ushort*)(ws + 33554432);               //  4,194,304 B
    ushort* qlb  = (ushort*)(ws + 37748736);               //  4,194,304 B
    ushort* khb  = (ushort*)(ws + 41943040);               // 16,777,216 B
    ushort* vthb = (ushort*)(ws + 58720256);               // 16,777,216 B
    float*  ybuf = (float*)(ws + 75497472);                //  8,388,608 B
    // total 83,886,080 B

    hipMemsetAsync(ybuf, 0, (size_t)ROWS_PL * DMODEL * sizeof(float), stream);

    dim3 blk(256);
    // Xs -> hi plane; weights -> hi+lo planes
    presplit<<<dim3(3072, 1, 6), blk, 0, stream>>>(x, lo, Wq, Wk, Wv, Wo, XsH, WH, WL);
    // Q projection -> hi/lo planes [b*16+h][s][e]
    proj_qo<0><<<dim3(16, 32), blk, 0, stream>>>(x, WH, WL, bq, nullptr, qhb, qlb);
    // fused K+V projection (glds-staged; K hi [bh][s][e]; V^T hi [bh][e][s])
    proj_kv<<<dim3(8, 128), blk, 0, stream>>>(XsH,
        WH + 1048576, WL + 1048576, WH + 2097152, WL + 2097152,
        bk, bv, khb, vthb);
    // attention: 512 XCD-swizzled blocks, 4 waves, wave = q64
    attn_mfma<<<dim3(512), blk, 0, stream>>>(qhb, qlb, khb, vthb, lw, ybuf);
    // output projection
    proj_qo<1><<<dim3(16, 32), blk, 0, stream>>>(ybuf, WH + 3145728, WL + 3145728, bo, out, nullptr, nullptr);
}

// Round 9
// 318.997 us; speedup vs baseline: 2.5445x; 1.0834x over previous
//
#include <hip/hip_runtime.h>
#include <hip/hip_bf16.h>
#include <math.h>

// Problem constants (fixed by reference setup)
#define S_LEN   1024
#define BATCH   2
#define DMODEL  1024
#define NHEADS  16
#define HDIM    64
#define BHEADS  32          // BATCH*NHEADS
#define LP1     4           // 1 + L layers
#define ROWS_PL 2048        // S*B rows per layer

typedef __attribute__((ext_vector_type(8)))  short bf16x8;   // 8 bf16 = 4 VGPRs
typedef __attribute__((ext_vector_type(4)))  float f32x4;
typedef __attribute__((ext_vector_type(16))) float f32x16;

__device__ inline ushort bf16_rne(float a) {
    unsigned u = __float_as_uint(a);
    return (ushort)((u + 0x7FFFu + ((u >> 16) & 1u)) >> 16);
}
__device__ inline float bf16_up(ushort h) { return __uint_as_float(((unsigned)h) << 16); }
__device__ inline void split_bf16(float a, ushort &hi, ushort &lo) {
    hi = bf16_rne(a);
    lo = bf16_rne(a - bf16_up(hi));
}
// packed f32x2 -> bf16x2 (v_cvt_pk_bf16_f32 where available)
__device__ inline uint pk_bf16(float a, float b) {
    float2 f; f.x = a; f.y = b;
    __hip_bfloat162 h = __float22bfloat162_rn(f);
    return *reinterpret_cast<uint*>(&h);
}

// Async global->LDS, 16 B per lane. HW places lane i at lds_base + i*16.
__device__ inline void glds16(const ushort* g, ushort* l) {
    __builtin_amdgcn_global_load_lds(
        (const __attribute__((address_space(1))) void*)g,
        (__attribute__((address_space(3))) void*)l, 16, 0, 0);
}

// hd^-0.5 * log2(e), folded into the Q projection epilogue
#define SCLF 0.18033688011112042f

// ---------------------------------------------------------------------------
// One-shot pre-split: Xs = [x ; layer_outputs] -> hi bf16 plane;
// weights -> hi+lo planes. z-demuxed single launch.
// ---------------------------------------------------------------------------
__global__ __launch_bounds__(256)
void presplit(const float* __restrict__ x, const float* __restrict__ lo,
              const float* __restrict__ Wq, const float* __restrict__ Wk,
              const float* __restrict__ Wv, const float* __restrict__ Wo,
              ushort* __restrict__ XsH, ushort* __restrict__ WH,
              ushort* __restrict__ WL)
{
    const int z = blockIdx.z;
    const float* src; ushort* dh; ushort* dl = nullptr; int n;
    if (z == 0)      { src = x;  dh = XsH;           n = 2097152; }
    else if (z == 1) { src = lo; dh = XsH + 2097152; n = 6291456; }
    else {
        const float* wsrc[4] = { Wq, Wk, Wv, Wo };
        src = wsrc[z - 2];
        dh = WH + (size_t)(z - 2) * 1048576;
        dl = WL + (size_t)(z - 2) * 1048576;
        n = 1048576;
    }
    const int i = (blockIdx.x * 256 + threadIdx.x) * 8;
    if (i >= n) return;
    float v[8];
    *(float4*)&v[0] = *(const float4*)(src + i);
    *(float4*)&v[4] = *(const float4*)(src + i + 4);
    ushort h[8];
    #pragma unroll
    for (int j = 0; j < 8; ++j) h[j] = bf16_rne(v[j]);
    *(uint4*)(dh + i) = *(uint4*)h;
    if (dl) {
        ushort l[8];
        #pragma unroll
        for (int j = 0; j < 8; ++j) l[j] = bf16_rne(v[j] - bf16_up(h[j]));
        *(uint4*)(dl + i) = *(uint4*)l;
    }
}

// ---------------------------------------------------------------------------
// Q / O projection, pure-glds staging. C[2048,1024] = A_hi @ (W_hi+W_lo)^T
// + bias. BM=BN=64, BK=32, 256 thr (2x2 waves, 2x2 frags). A is a bf16 hi
// plane (XsH x-part for Q; YH for O). Flat grid 512, XCD-swizzled so the 32
// m-blocks of each n-column co-locate (weight slice stays L2-local).
// MODE 0: scale by SCLF, split hi/lo planes at [b*16+h][s][e]  (Q)
// MODE 1: fp32 row-major out[m][n]                             (O)
// ---------------------------------------------------------------------------
template<int MODE>
__global__ __launch_bounds__(256)
void proj_g(const ushort* __restrict__ Abf,
            const ushort* __restrict__ Bhg, const ushort* __restrict__ Blg,
            const float* __restrict__ bias,
            float* __restrict__ outf, ushort* __restrict__ outh,
            ushort* __restrict__ outl)
{
    __shared__ ushort smem[3 * 2048];    // Ah, Bh, Bl: [64][32]
    ushort* Ah = smem;
    ushort* Bh = smem + 2048;
    ushort* Bl = smem + 4096;

    const int fid = blockIdx.x;
    const int nt = (fid & 7) * 2 + ((fid >> 3) & 1);
    const int mt = fid >> 4;
    const int m0 = mt * 64, n0 = nt * 64;

    const int t  = threadIdx.x;
    const int wv = t >> 6, lane = t & 63;
    const int quad = lane >> 4, r = lane & 15;
    const int wm = wv & 1, wn = wv >> 1;
    const int mBase = wm * 32, nBase = wn * 32;

    const int lrow = lane >> 2, lch = (lane & 3) * 8;
    const ushort* Asrc  = Abf + (size_t)(m0 + wv * 16 + lrow) * DMODEL + lch;
    const ushort* Bhsrc = Bhg + (size_t)(n0 + wv * 16 + lrow) * DMODEL + lch;
    const ushort* Blsrc = Blg + (size_t)(n0 + wv * 16 + lrow) * DMODEL + lch;
    ushort* lA  = Ah + wv * 16 * 32;
    ushort* lBh = Bh + wv * 16 * 32;
    ushort* lBl = Bl + wv * 16 * 32;

    f32x4 acc[2][2];
    #pragma unroll
    for (int i = 0; i < 2; ++i)
        #pragma unroll
        for (int j = 0; j < 2; ++j) acc[i][j] = (f32x4){0.f, 0.f, 0.f, 0.f};

    for (int k0 = 0; k0 < DMODEL; k0 += 32) {
        glds16(Asrc + k0, lA);
        glds16(Bhsrc + k0, lBh);
        glds16(Blsrc + k0, lBl);
        __syncthreads();   // drains vmcnt -> staged data visible
        bf16x8 fa[2], fbh[2], fbl[2];
        #pragma unroll
        for (int i = 0; i < 2; ++i)
            fa[i] = *(const bf16x8*)&Ah[(mBase + i * 16 + r) * 32 + quad * 8];
        #pragma unroll
        for (int j = 0; j < 2; ++j) {
            fbh[j] = *(const bf16x8*)&Bh[(nBase + j * 16 + r) * 32 + quad * 8];
            fbl[j] = *(const bf16x8*)&Bl[(nBase + j * 16 + r) * 32 + quad * 8];
        }
        #pragma unroll
        for (int i = 0; i < 2; ++i)
            #pragma unroll
            for (int j = 0; j < 2; ++j) {
                acc[i][j] = __builtin_amdgcn_mfma_f32_16x16x32_bf16(fa[i], fbh[j], acc[i][j], 0, 0, 0);
                acc[i][j] = __builtin_amdgcn_mfma_f32_16x16x32_bf16(fa[i], fbl[j], acc[i][j], 0, 0, 0);
            }
        __syncthreads();   // LDS consumed before next iteration's glds
    }

    const int cn = lane & 15;
    #pragma unroll
    for (int j = 0; j < 2; ++j) {
        const int n = n0 + nBase + j * 16 + cn;
        const float bv = bias[n];
        #pragma unroll
        for (int i = 0; i < 2; ++i) {
            const int mrow = m0 + mBase + i * 16 + quad * 4;
            #pragma unroll
            for (int g = 0; g < 4; ++g) {
                const int m = mrow + g;
                if (MODE == 1) {
                    outf[(size_t)m * DMODEL + n] = acc[i][j][g] + bv;
                } else {
                    const float val = (acc[i][j][g] + bv) * SCLF;   // fold attn scale
                    const int s = m >> 1, b = m & 1;
                    const int bh = b * 16 + (n >> 6), e = n & 63;
                    const size_t idx = (((size_t)bh * S_LEN) + s) * HDIM + e;
                    ushort hi, lov; split_bf16(val, hi, lov);
                    outh[idx] = hi; outl[idx] = lov;
                }
            }
        }
    }
}

// ---------------------------------------------------------------------------
// Fused K+V projection, glds staging (unchanged from R8 — verified).
// ---------------------------------------------------------------------------
__global__ __launch_bounds__(256, 4)
void proj_kv(const ushort* __restrict__ XsH,
             const ushort* __restrict__ KWh, const ushort* __restrict__ KWl,
             const ushort* __restrict__ VWh, const ushort* __restrict__ VWl,
             const float* __restrict__ bk, const float* __restrict__ bv,
             ushort* __restrict__ kout, ushort* __restrict__ vout)
{
    __shared__ ushort smem[18432];       // Ah 64x32 + 4 planes 128x32 = 36 KB
    ushort* Ah = smem;                   // [64][32]
    ushort* Bp = smem + 2048;            // [plane][128][32]

    const int t  = threadIdx.x;
    const int m0 = blockIdx.y * 64, n0 = blockIdx.x * 128;
    const int lyr = m0 >> 11;

    const int wv = t >> 6, lane = t & 63;
    const int quad = lane >> 4, r = lane & 15;
    const int wm = wv & 1, wn = wv >> 1;
    const int mBase = wm * 32, nBase = wn * 64;

    const int lrow = lane >> 2, lch = (lane & 3) * 8;

    const ushort* Asrc = XsH + (size_t)(m0 + wv * 16 + lrow) * DMODEL + lch;
    const ushort* Bw[4] = { KWh, KWl, VWh, VWl };
    const ushort* Bsrc[4][2];
    #pragma unroll
    for (int p = 0; p < 4; ++p)
        #pragma unroll
        for (int seg = 0; seg < 2; ++seg)
            Bsrc[p][seg] = Bw[p] + (size_t)(n0 + wv * 32 + seg * 16 + lrow) * DMODEL + lch;

    f32x4 aK[2][4], aV[2][4];
    #pragma unroll
    for (int i = 0; i < 2; ++i)
        #pragma unroll
        for (int j = 0; j < 4; ++j) {
            aK[i][j] = (f32x4){0.f, 0.f, 0.f, 0.f};
            aV[i][j] = (f32x4){0.f, 0.f, 0.f, 0.f};
        }

    for (int k0 = 0; k0 < DMODEL; k0 += 32) {
        glds16(Asrc + k0, Ah + (wv * 16) * 32);
        #pragma unroll
        for (int p = 0; p < 4; ++p)
            #pragma unroll
            for (int seg = 0; seg < 2; ++seg)
                glds16(Bsrc[p][seg] + k0,
                       Bp + p * 4096 + (wv * 32 + seg * 16) * 32);
        __syncthreads();

        bf16x8 fa[2];
        #pragma unroll
        for (int i = 0; i < 2; ++i)
            fa[i] = *(const bf16x8*)&Ah[(mBase + i * 16 + r) * 32 + quad * 8];
        #pragma unroll
        for (int j = 0; j < 4; ++j) {
            const int rowb = (nBase + j * 16 + r) * 32 + quad * 8;
            const bf16x8 fkh = *(const bf16x8*)&Bp[rowb];
            const bf16x8 fkl = *(const bf16x8*)&Bp[4096 + rowb];
            #pragma unroll
            for (int i = 0; i < 2; ++i) {
                aK[i][j] = __builtin_amdgcn_mfma_f32_16x16x32_bf16(fa[i], fkh, aK[i][j], 0, 0, 0);
                aK[i][j] = __builtin_amdgcn_mfma_f32_16x16x32_bf16(fa[i], fkl, aK[i][j], 0, 0, 0);
            }
            const bf16x8 fvh = *(const bf16x8*)&Bp[8192 + rowb];
            const bf16x8 fvl = *(const bf16x8*)&Bp[12288 + rowb];
            #pragma unroll
            for (int i = 0; i < 2; ++i) {
                aV[i][j] = __builtin_amdgcn_mfma_f32_16x16x32_bf16(fa[i], fvh, aV[i][j], 0, 0, 0);
                aV[i][j] = __builtin_amdgcn_mfma_f32_16x16x32_bf16(fa[i], fvl, aV[i][j], 0, 0, 0);
            }
        }
        __syncthreads();
    }

    const int cn = lane & 15;

    #pragma unroll
    for (int j = 0; j < 4; ++j) {
        const int n = n0 + nBase + j * 16 + cn;
        const float bb = bk[n];
        #pragma unroll
        for (int i = 0; i < 2; ++i) {
            #pragma unroll
            for (int g = 0; g < 4; ++g) {
                const int m = m0 + mBase + i * 16 + quad * 4 + g;
                const int rem = m & 2047, s = rem >> 1, b = rem & 1;
                const int bh = lyr * 32 + b * 16 + (n >> 6);
                kout[(((size_t)bh * S_LEN) + s) * HDIM + (n & 63)] = bf16_rne(aK[i][j][g] + bb);
            }
        }
    }

    ushort* T = smem;   // [128][66]
    #pragma unroll
    for (int j = 0; j < 4; ++j) {
        const int nloc = nBase + j * 16 + cn;
        const float bb = bv[n0 + nloc];
        #pragma unroll
        for (int i = 0; i < 2; ++i) {
            #pragma unroll
            for (int g = 0; g < 4; ++g) {
                const int mloc = mBase + i * 16 + quad * 4 + g;
                T[nloc * 66 + mloc] = bf16_rne(aV[i][j][g] + bb);
            }
        }
    }
    __syncthreads();
    {
        const int nloc = t >> 1, bsel = t & 1;
        const int n = n0 + nloc, h = n >> 6, e = n & 63;
        const int s0g = (m0 & 2047) >> 1;
        const int bhI = lyr * 32 + bsel * 16 + h;
        ushort* dst = vout + ((size_t)bhI * HDIM + e) * S_LEN + s0g;
        #pragma unroll
        for (int c = 0; c < 4; ++c) {
            ushort tmp[8];
            #pragma unroll
            for (int j = 0; j < 8; ++j)
                tmp[j] = T[nloc * 66 + 2 * (c * 8 + j) + bsel];
            *(uint4*)(dst + c * 8) = *(uint4*)tmp;
        }
    }
}

// ---------------------------------------------------------------------------
// MFMA flash attention. Block = 4 waves, wave owns q=64. Grid 512 flat,
// XCD-swizzled. K/V hi-plane only; Q hi+lo (pre-scaled by SCLF) in regs.
// Softmax diet: P = exp2(sa) (scale folded into Q), packed bf16 cvt, P tile
// stored in A-layout [q][k] (stride 40, 16B-aligned) -> PV frag = 1
// ds_read_b128. No atomics: per-layer partials to part[l] (fp32 stores).
// ---------------------------------------------------------------------------
__global__ __launch_bounds__(256, 2)
void attn_mfma(const ushort* __restrict__ qhg, const ushort* __restrict__ qlg,
               const ushort* __restrict__ kh, const ushort* __restrict__ vth,
               const float* __restrict__ lwraw, float* __restrict__ part)
{
    __shared__ ushort Pa[8 * 1280];   // [wave*2+u][q=32][k=32 pad 40] = 20,480 B

    const int t    = threadIdx.x;
    const int wv   = t >> 6, lane = t & 63;
    const int half = lane >> 5, lid = lane & 31;

    const int fid  = blockIdx.x;
    const int xcd  = fid & 7, slot = fid >> 3;
    const int pair = xcd * 16 + (slot >> 2);     // 16 (bh,l) pairs per XCD
    const int qt   = slot & 3;
    const int bh   = pair & 31, l = pair >> 5;
    const int qbase = qt * 256 + wv * 64;

    float wl;
    {
        float v[LP1], wm = -3.0e38f;
        #pragma unroll
        for (int i = 0; i < LP1; ++i) { v[i] = lwraw[i]; wm = fmaxf(wm, v[i]); }
        float ws = 0.f;
        #pragma unroll
        for (int i = 0; i < LP1; ++i) { v[i] = __expf(v[i] - wm); ws += v[i]; }
        wl = v[l] / ws;
    }

    bf16x8 qh[2][4], ql[2][4];
    #pragma unroll
    for (int u = 0; u < 2; ++u) {
        const size_t qoff = ((size_t)bh * S_LEN + qbase + u * 32 + lid) * HDIM + half * 8;
        #pragma unroll
        for (int es = 0; es < 4; ++es) {
            qh[u][es] = *(const bf16x8*)(qhg + qoff + es * 16);
            ql[u][es] = *(const bf16x8*)(qlg + qoff + es * 16);
        }
    }

    f32x16 o[2][2];
    #pragma unroll
    for (int u = 0; u < 2; ++u)
        #pragma unroll
        for (int d = 0; d < 2; ++d)
            #pragma unroll
            for (int i = 0; i < 16; ++i) o[u][d][i] = 0.f;
    float ls[2][16];
    #pragma unroll
    for (int u = 0; u < 2; ++u)
        #pragma unroll
        for (int i = 0; i < 16; ++i) ls[u][i] = 0.f;

    const size_t kvo = (size_t)(l * BHEADS + bh) * S_LEN * HDIM;

    for (int kt = 0; kt < 16; ++kt) {
        #pragma unroll
        for (int kc = 0; kc < 2; ++kc) {
            bf16x8 kb[4];
            #pragma unroll
            for (int es = 0; es < 4; ++es)
                kb[es] = *(const bf16x8*)(kh + kvo
                          + (size_t)(kt * 64 + kc * 32 + lid) * HDIM + es * 16 + half * 8);

            f32x16 sa[2];
            #pragma unroll
            for (int u = 0; u < 2; ++u)
                #pragma unroll
                for (int i = 0; i < 16; ++i) sa[u][i] = 0.f;
            #pragma unroll
            for (int es = 0; es < 4; ++es)
                #pragma unroll
                for (int u = 0; u < 2; ++u) {
                    sa[u] = __builtin_amdgcn_mfma_f32_32x32x16_bf16(qh[u][es], kb[es], sa[u], 0, 0, 0);
                    sa[u] = __builtin_amdgcn_mfma_f32_32x32x16_bf16(ql[u][es], kb[es], sa[u], 0, 0, 0);
                }

            bf16x8 vb[2][2];
            #pragma unroll
            for (int ks = 0; ks < 2; ++ks)
                #pragma unroll
                for (int dg = 0; dg < 2; ++dg)
                    vb[ks][dg] = *(const bf16x8*)(vth + kvo
                                  + (size_t)(dg * 32 + lid) * S_LEN
                                  + kt * 64 + kc * 32 + ks * 16 + half * 8);

            // P = exp2(sa); row sums; packed cvt; A-layout LDS write [q][k]
            #pragma unroll
            for (int u = 0; u < 2; ++u) {
                ushort* base = &Pa[(wv * 2 + u) * 1280];
                #pragma unroll
                for (int rr = 0; rr < 16; rr += 2) {
                    const float p0 = exp2f(sa[u][rr]);
                    const float p1 = exp2f(sa[u][rr + 1]);
                    ls[u][rr]     += p0;
                    ls[u][rr + 1] += p1;
                    const uint pb = pk_bf16(p0, p1);
                    const int q0 = (rr & 3) + 8 * (rr >> 2) + 4 * half;
                    base[q0 * 40 + lid]       = (ushort)pb;
                    base[(q0 + 1) * 40 + lid] = (ushort)(pb >> 16);
                }
            }

            // O += P V  (A-frag = 1 ds_read_b128 per (ks,u))
            #pragma unroll
            for (int ks = 0; ks < 2; ++ks)
                #pragma unroll
                for (int u = 0; u < 2; ++u) {
                    const bf16x8 pf = *(const bf16x8*)
                        &Pa[(wv * 2 + u) * 1280 + lid * 40 + ks * 16 + half * 8];
                    #pragma unroll
                    for (int dg = 0; dg < 2; ++dg)
                        o[u][dg] = __builtin_amdgcn_mfma_f32_32x32x16_bf16(pf, vb[ks][dg], o[u][dg], 0, 0, 0);
                }
        }
    }

    #pragma unroll
    for (int u = 0; u < 2; ++u)
        #pragma unroll
        for (int rr = 0; rr < 16; ++rr) {
            float v = ls[u][rr];
            #pragma unroll
            for (int off = 1; off < 32; off <<= 1) v += __shfl_xor(v, off, 32);
            ls[u][rr] = v;
        }

    // ---- epilogue: plain fp32 stores of this layer's partial ----
    const int b = bh >> 4, hh = bh & 15;
    float* pbase = part + (size_t)l * (ROWS_PL * DMODEL);
    #pragma unroll
    for (int u = 0; u < 2; ++u)
        #pragma unroll
        for (int rr = 0; rr < 16; ++rr) {
            const int q = qbase + u * 32 + 8 * (rr >> 2) + 4 * half + (rr & 3);
            const float sc = wl / ls[u][rr];
            #pragma unroll
            for (int dg = 0; dg < 2; ++dg) {
                const int d = hh * HDIM + dg * 32 + lid;
                pbase[((size_t)q * BATCH + b) * DMODEL + d] = o[u][dg][rr] * sc;
            }
        }
}

// ---------------------------------------------------------------------------
// Sum the 4 layer partials -> bf16 hi plane for the O projection.
// ---------------------------------------------------------------------------
__global__ __launch_bounds__(256)
void sum_y(const float* __restrict__ part, ushort* __restrict__ YH)
{
    const int i = (blockIdx.x * 256 + threadIdx.x) * 8;
    float acc[8];
    #pragma unroll
    for (int c = 0; c < 2; ++c) {
        float4 s = *(const float4*)(part + i + c * 4);
        #pragma unroll
        for (int l = 1; l < LP1; ++l) {
            const float4 p = *(const float4*)(part + (size_t)l * 2097152 + i + c * 4);
            s.x += p.x; s.y += p.y; s.z += p.z; s.w += p.w;
        }
        acc[c * 4 + 0] = s.x; acc[c * 4 + 1] = s.y;
        acc[c * 4 + 2] = s.z; acc[c * 4 + 3] = s.w;
    }
    uint out[4];
    #pragma unroll
    for (int c = 0; c < 4; ++c) out[c] = pk_bf16(acc[c * 2], acc[c * 2 + 1]);
    *(uint4*)(YH + i) = *(uint4*)out;
}

// ---------------------------------------------------------------------------
extern "C" void kernel_launch(void* const* d_in, const int* in_sizes, int n_in,
                              void* d_out, int out_size, void* d_ws, size_t ws_size,
                              hipStream_t stream) {
    const float* x  = (const float*)d_in[0];
    const float* lo = (const float*)d_in[1];
    const float* Wq = (const float*)d_in[2];
    const float* bq = (const float*)d_in[3];
    const float* Wk = (const float*)d_in[4];
    const float* bk = (const float*)d_in[5];
    const float* Wv = (const float*)d_in[6];
    const float* bv = (const float*)d_in[7];
    const float* Wo = (const float*)d_in[8];
    const float* bo = (const float*)d_in[9];
    const float* lw = (const float*)d_in[10];
    float* out = (float*)d_out;

    char* ws = (char*)d_ws;
    ushort* XsH  = (ushort*)(ws);                          // 16,777,216 B
    ushort* WH   = (ushort*)(ws + 16777216);               //  8,388,608 B
    ushort* WL   = (ushort*)(ws + 25165824);               //  8,388,608 B
    ushort* qhb  = (ushort*)(ws + 33554432);               //  4,194,304 B
    ushort* qlb  = (ushort*)(ws + 37748736);               //  4,194,304 B
    ushort* khb  = (ushort*)(ws + 41943040);               // 16,777,216 B
    ushort* vthb = (ushort*)(ws + 58720256);               // 16,777,216 B
    float*  part = (float*)(ws + 75497472);                // 33,554,432 B
    ushort* YH   = (ushort*)(ws + 109051904);              //  4,194,304 B
    // total 113,246,208 B

    dim3 blk(256);
    // Xs -> hi plane; weights -> hi+lo planes
    presplit<<<dim3(3072, 1, 6), blk, 0, stream>>>(x, lo, Wq, Wk, Wv, Wo, XsH, WH, WL);
    // Q projection (glds): pre-scaled hi/lo planes [b*16+h][s][e]
    proj_g<0><<<dim3(512), blk, 0, stream>>>(XsH, WH, WL, bq, nullptr, qhb, qlb);
    // fused K+V projection (glds; K hi [bh][s][e]; V^T hi [bh][e][s])
    proj_kv<<<dim3(8, 128), blk, 0, stream>>>(XsH,
        WH + 1048576, WL + 1048576, WH + 2097152, WL + 2097152,
        bk, bv, khb, vthb);
    // attention: 512 XCD-swizzled blocks -> per-layer fp32 partials
    attn_mfma<<<dim3(512), blk, 0, stream>>>(qhb, qlb, khb, vthb, lw, part);
    // reduce 4 partials -> bf16 hi plane
    sum_y<<<dim3(1024), blk, 0, stream>>>(part, YH);
    // output projection (glds)
    proj_g<1><<<dim3(512), blk, 0, stream>>>(YH, WH + 3145728, WL + 3145728, bo, out, nullptr, nullptr);
}

// Round 10
// 275.815 us; speedup vs baseline: 2.9429x; 1.1566x over previous
//
#include <hip/hip_runtime.h>
#include <hip/hip_bf16.h>
#include <math.h>

// Problem constants (fixed by reference setup)
#define S_LEN   1024
#define BATCH   2
#define DMODEL  1024
#define NHEADS  16
#define HDIM    64
#define BHEADS  32          // BATCH*NHEADS
#define LP1     4           // 1 + L layers
#define ROWS_PL 2048        // S*B rows per layer

typedef __attribute__((ext_vector_type(8)))  short bf16x8;   // 8 bf16 = 4 VGPRs
typedef __attribute__((ext_vector_type(4)))  float f32x4;
typedef __attribute__((ext_vector_type(16))) float f32x16;

__device__ inline ushort bf16_rne(float a) {
    unsigned u = __float_as_uint(a);
    return (ushort)((u + 0x7FFFu + ((u >> 16) & 1u)) >> 16);
}
__device__ inline float bf16_up(ushort h) { return __uint_as_float(((unsigned)h) << 16); }
__device__ inline void split_bf16(float a, ushort &hi, ushort &lo) {
    hi = bf16_rne(a);
    lo = bf16_rne(a - bf16_up(hi));
}
// packed f32x2 -> bf16x2 (v_cvt_pk_bf16_f32)
__device__ inline uint pk_bf16(float a, float b) {
    float2 f; f.x = a; f.y = b;
    __hip_bfloat162 h = __float22bfloat162_rn(f);
    return *reinterpret_cast<uint*>(&h);
}
// raw v_exp_f32 (no denormal fixup path)
#if __has_builtin(__builtin_amdgcn_exp2f)
__device__ inline float fast_exp2(float x) { return __builtin_amdgcn_exp2f(x); }
#else
__device__ inline float fast_exp2(float x) { return exp2f(x); }
#endif

// Async global->LDS, 16 B per lane. HW places lane i at lds_base + i*16.
__device__ inline void glds16(const ushort* g, ushort* l) {
    __builtin_amdgcn_global_load_lds(
        (const __attribute__((address_space(1))) void*)g,
        (__attribute__((address_space(3))) void*)l, 16, 0, 0);
}

// hd^-0.5 * log2(e), folded into the Q projection epilogue
#define SCLF 0.18033688011112042f

// ---------------------------------------------------------------------------
// One-shot pre-split: Xs = [x ; layer_outputs] -> hi bf16 plane;
// Wq/Wo -> hi+lo planes; Wk/Wv -> hi plane only (lo dropped: its contribution
// is below the bf16 rounding already applied to K/V outputs).
// ---------------------------------------------------------------------------
__global__ __launch_bounds__(256)
void presplit(const float* __restrict__ x, const float* __restrict__ lo,
              const float* __restrict__ Wq, const float* __restrict__ Wk,
              const float* __restrict__ Wv, const float* __restrict__ Wo,
              ushort* __restrict__ XsH, ushort* __restrict__ WH,
              ushort* __restrict__ WL)
{
    const int z = blockIdx.z;
    const float* src; ushort* dh; ushort* dl = nullptr; int n;
    if (z == 0)      { src = x;  dh = XsH;           n = 2097152; }
    else if (z == 1) { src = lo; dh = XsH + 2097152; n = 6291456; }
    else {
        const float* wsrc[4] = { Wq, Wk, Wv, Wo };
        src = wsrc[z - 2];
        dh = WH + (size_t)(z - 2) * 1048576;
        if (z == 2 || z == 5) dl = WL + (size_t)(z - 2) * 1048576;
        n = 1048576;
    }
    const int i = (blockIdx.x * 256 + threadIdx.x) * 8;
    if (i >= n) return;
    float v[8];
    *(float4*)&v[0] = *(const float4*)(src + i);
    *(float4*)&v[4] = *(const float4*)(src + i + 4);
    ushort h[8];
    #pragma unroll
    for (int j = 0; j < 8; ++j) h[j] = bf16_rne(v[j]);
    *(uint4*)(dh + i) = *(uint4*)h;
    if (dl) {
        ushort l[8];
        #pragma unroll
        for (int j = 0; j < 8; ++j) l[j] = bf16_rne(v[j] - bf16_up(h[j]));
        *(uint4*)(dl + i) = *(uint4*)l;
    }
}

// ---------------------------------------------------------------------------
// Q / O projection, glds staging with XOR chunk swizzle (lane i fetches
// chunk (i&3)^((i>>2)&3): same 64 B lines, bank-friendly frag reads).
// C[2048,1024] = A_hi @ (W_hi+W_lo)^T + bias. BM=BN=64, BK=32, 256 thr.
// MODE 0: scale by SCLF, split hi/lo planes at [b*16+h][s][e]  (Q)
// MODE 1: fp32 row-major out[m][n]                             (O)
// ---------------------------------------------------------------------------
template<int MODE>
__global__ __launch_bounds__(256)
void proj_g(const ushort* __restrict__ Abf,
            const ushort* __restrict__ Bhg, const ushort* __restrict__ Blg,
            const float* __restrict__ bias,
            float* __restrict__ outf, ushort* __restrict__ outh,
            ushort* __restrict__ outl)
{
    __shared__ ushort smem[3 * 2048];    // Ah, Bh, Bl: [64][32]
    ushort* Ah = smem;
    ushort* Bh = smem + 2048;
    ushort* Bl = smem + 4096;

    const int fid = blockIdx.x;
    const int nt = (fid & 7) * 2 + ((fid >> 3) & 1);
    const int mt = fid >> 4;
    const int m0 = mt * 64, n0 = nt * 64;

    const int t  = threadIdx.x;
    const int wv = t >> 6, lane = t & 63;
    const int quad = lane >> 4, r = lane & 15;
    const int wm = wv & 1, wn = wv >> 1;
    const int mBase = wm * 32, nBase = wn * 32;

    const int lrow = lane >> 2;
    const int lch  = ((lane & 3) ^ (lrow & 3)) * 8;      // XOR chunk swizzle
    const ushort* Asrc  = Abf + (size_t)(m0 + wv * 16 + lrow) * DMODEL + lch;
    const ushort* Bhsrc = Bhg + (size_t)(n0 + wv * 16 + lrow) * DMODEL + lch;
    const ushort* Blsrc = Blg + (size_t)(n0 + wv * 16 + lrow) * DMODEL + lch;
    ushort* lA  = Ah + wv * 512;
    ushort* lBh = Bh + wv * 512;
    ushort* lBl = Bl + wv * 512;

    const int q0x = (quad ^ (r & 3)) << 3;               // swizzled frag chunk
    f32x4 acc[2][2];
    #pragma unroll
    for (int i = 0; i < 2; ++i)
        #pragma unroll
        for (int j = 0; j < 2; ++j) acc[i][j] = (f32x4){0.f, 0.f, 0.f, 0.f};

    for (int k0 = 0; k0 < DMODEL; k0 += 32) {
        glds16(Asrc + k0, lA);
        glds16(Bhsrc + k0, lBh);
        glds16(Blsrc + k0, lBl);
        __syncthreads();   // drains vmcnt -> staged data visible
        bf16x8 fa[2], fbh[2], fbl[2];
        #pragma unroll
        for (int i = 0; i < 2; ++i)
            fa[i] = *(const bf16x8*)&Ah[(mBase + i * 16 + r) * 32 + q0x];
        #pragma unroll
        for (int j = 0; j < 2; ++j) {
            fbh[j] = *(const bf16x8*)&Bh[(nBase + j * 16 + r) * 32 + q0x];
            fbl[j] = *(const bf16x8*)&Bl[(nBase + j * 16 + r) * 32 + q0x];
        }
        #pragma unroll
        for (int i = 0; i < 2; ++i)
            #pragma unroll
            for (int j = 0; j < 2; ++j) {
                acc[i][j] = __builtin_amdgcn_mfma_f32_16x16x32_bf16(fa[i], fbh[j], acc[i][j], 0, 0, 0);
                acc[i][j] = __builtin_amdgcn_mfma_f32_16x16x32_bf16(fa[i], fbl[j], acc[i][j], 0, 0, 0);
            }
        __syncthreads();   // LDS consumed before next iteration's glds
    }

    const int cn = lane & 15;
    #pragma unroll
    for (int j = 0; j < 2; ++j) {
        const int n = n0 + nBase + j * 16 + cn;
        const float bv = bias[n];
        #pragma unroll
        for (int i = 0; i < 2; ++i) {
            const int mrow = m0 + mBase + i * 16 + quad * 4;
            #pragma unroll
            for (int g = 0; g < 4; ++g) {
                const int m = mrow + g;
                if (MODE == 1) {
                    outf[(size_t)m * DMODEL + n] = acc[i][j][g] + bv;
                } else {
                    const float val = (acc[i][j][g] + bv) * SCLF;   // fold attn scale
                    const int s = m >> 1, b = m & 1;
                    const int bh = b * 16 + (n >> 6), e = n & 63;
                    const size_t idx = (((size_t)bh * S_LEN) + s) * HDIM + e;
                    ushort hi, lov; split_bf16(val, hi, lov);
                    outh[idx] = hi; outl[idx] = lov;
                }
            }
        }
    }
}

// ---------------------------------------------------------------------------
// Fused K+V projection, glds staging, hi-only weights (2 B planes), XOR
// chunk swizzle. BM=64, BN=128, BK=32, 256 thr (2x2 waves). LDS 20 KB.
// K epilogue: hi plane at [l*32+b*16+h][s][e]
// V epilogue: hi plane at [l*32+b*16+h][e][s] via LDS transpose.
// ---------------------------------------------------------------------------
__global__ __launch_bounds__(256, 4)
void proj_kv(const ushort* __restrict__ XsH,
             const ushort* __restrict__ KWh, const ushort* __restrict__ VWh,
             const float* __restrict__ bk, const float* __restrict__ bv,
             ushort* __restrict__ kout, ushort* __restrict__ vout)
{
    __shared__ ushort smem[10240];       // Ah 64x32 + 2 planes 128x32 = 20 KB
    ushort* Ah = smem;                   // [64][32]
    ushort* Bp = smem + 2048;            // [plane][128][32]

    const int t  = threadIdx.x;
    const int m0 = blockIdx.y * 64, n0 = blockIdx.x * 128;
    const int lyr = m0 >> 11;

    const int wv = t >> 6, lane = t & 63;
    const int quad = lane >> 4, r = lane & 15;
    const int wm = wv & 1, wn = wv >> 1;
    const int mBase = wm * 32, nBase = wn * 64;

    const int lrow = lane >> 2;
    const int lch  = ((lane & 3) ^ (lrow & 3)) * 8;      // XOR chunk swizzle

    const ushort* Asrc = XsH + (size_t)(m0 + wv * 16 + lrow) * DMODEL + lch;
    const ushort* Bw[2] = { KWh, VWh };
    const ushort* Bsrc[2][2];
    #pragma unroll
    for (int p = 0; p < 2; ++p)
        #pragma unroll
        for (int seg = 0; seg < 2; ++seg)
            Bsrc[p][seg] = Bw[p] + (size_t)(n0 + wv * 32 + seg * 16 + lrow) * DMODEL + lch;

    const int q0x = (quad ^ (r & 3)) << 3;

    f32x4 aK[2][4], aV[2][4];
    #pragma unroll
    for (int i = 0; i < 2; ++i)
        #pragma unroll
        for (int j = 0; j < 4; ++j) {
            aK[i][j] = (f32x4){0.f, 0.f, 0.f, 0.f};
            aV[i][j] = (f32x4){0.f, 0.f, 0.f, 0.f};
        }

    for (int k0 = 0; k0 < DMODEL; k0 += 32) {
        glds16(Asrc + k0, Ah + wv * 512);
        #pragma unroll
        for (int p = 0; p < 2; ++p)
            #pragma unroll
            for (int seg = 0; seg < 2; ++seg)
                glds16(Bsrc[p][seg] + k0, Bp + p * 4096 + (wv * 2 + seg) * 512);
        __syncthreads();

        bf16x8 fa[2];
        #pragma unroll
        for (int i = 0; i < 2; ++i)
            fa[i] = *(const bf16x8*)&Ah[(mBase + i * 16 + r) * 32 + q0x];
        #pragma unroll
        for (int j = 0; j < 4; ++j) {
            const int off = (nBase + j * 16 + r) * 32 + q0x;
            const bf16x8 fkh = *(const bf16x8*)&Bp[off];
            const bf16x8 fvh = *(const bf16x8*)&Bp[4096 + off];
            #pragma unroll
            for (int i = 0; i < 2; ++i) {
                aK[i][j] = __builtin_amdgcn_mfma_f32_16x16x32_bf16(fa[i], fkh, aK[i][j], 0, 0, 0);
                aV[i][j] = __builtin_amdgcn_mfma_f32_16x16x32_bf16(fa[i], fvh, aV[i][j], 0, 0, 0);
            }
        }
        __syncthreads();
    }

    const int cn = lane & 15;

    // ---- K epilogue: hi plane, [l*32+b*16+h][s][e] ----
    #pragma unroll
    for (int j = 0; j < 4; ++j) {
        const int n = n0 + nBase + j * 16 + cn;
        const float bb = bk[n];
        #pragma unroll
        for (int i = 0; i < 2; ++i) {
            #pragma unroll
            for (int g = 0; g < 4; ++g) {
                const int m = m0 + mBase + i * 16 + quad * 4 + g;
                const int rem = m & 2047, s = rem >> 1, b = rem & 1;
                const int bh = lyr * 32 + b * 16 + (n >> 6);
                kout[(((size_t)bh * S_LEN) + s) * HDIM + (n & 63)] = bf16_rne(aK[i][j][g] + bb);
            }
        }
    }

    // ---- V epilogue: transpose via LDS, coalesced stores ----
    ushort* T = smem;   // [128][66] = 8448 ushorts <= 10240
    __syncthreads();
    #pragma unroll
    for (int j = 0; j < 4; ++j) {
        const int nloc = nBase + j * 16 + cn;
        const float bb = bv[n0 + nloc];
        #pragma unroll
        for (int i = 0; i < 2; ++i) {
            #pragma unroll
            for (int g = 0; g < 4; ++g) {
                const int mloc = mBase + i * 16 + quad * 4 + g;
                T[nloc * 66 + mloc] = bf16_rne(aV[i][j][g] + bb);
            }
        }
    }
    __syncthreads();
    {
        const int nloc = t >> 1, bsel = t & 1;
        const int n = n0 + nloc, h = n >> 6, e = n & 63;
        const int s0g = (m0 & 2047) >> 1;
        const int bhI = lyr * 32 + bsel * 16 + h;
        ushort* dst = vout + ((size_t)bhI * HDIM + e) * S_LEN + s0g;
        #pragma unroll
        for (int c = 0; c < 4; ++c) {
            ushort tmp[8];
            #pragma unroll
            for (int j = 0; j < 8; ++j)
                tmp[j] = T[nloc * 66 + 2 * (c * 8 + j) + bsel];
            *(uint4*)(dst + c * 8) = *(uint4*)tmp;
        }
    }
}

// ---------------------------------------------------------------------------
// MFMA flash attention. Block = 4 waves, wave owns q=64. Grid 512 flat,
// XCD-swizzled. K/V hi-plane only; Q hi+lo (pre-scaled by SCLF) in regs.
// P = exp2(sa) via raw v_exp_f32; packed bf16 cvt; P tile in A-layout
// [q][k pad 40] -> PV frag = 1 ds_read_b128. Per-layer fp32 partials.
// ---------------------------------------------------------------------------
__global__ __launch_bounds__(256, 2)
void attn_mfma(const ushort* __restrict__ qhg, const ushort* __restrict__ qlg,
               const ushort* __restrict__ kh, const ushort* __restrict__ vth,
               const float* __restrict__ lwraw, float* __restrict__ part)
{
    __shared__ ushort Pa[8 * 1280];   // [wave*2+u][q=32][k=32 pad 40] = 20,480 B

    const int t    = threadIdx.x;
    const int wv   = t >> 6, lane = t & 63;
    const int half = lane >> 5, lid = lane & 31;

    const int fid  = blockIdx.x;
    const int xcd  = fid & 7, slot = fid >> 3;
    const int pair = xcd * 16 + (slot >> 2);     // 16 (bh,l) pairs per XCD
    const int qt   = slot & 3;
    const int bh   = pair & 31, l = pair >> 5;
    const int qbase = qt * 256 + wv * 64;

    float wl;
    {
        float v[LP1], wm = -3.0e38f;
        #pragma unroll
        for (int i = 0; i < LP1; ++i) { v[i] = lwraw[i]; wm = fmaxf(wm, v[i]); }
        float ws = 0.f;
        #pragma unroll
        for (int i = 0; i < LP1; ++i) { v[i] = __expf(v[i] - wm); ws += v[i]; }
        wl = v[l] / ws;
    }

    bf16x8 qh[2][4], ql[2][4];
    #pragma unroll
    for (int u = 0; u < 2; ++u) {
        const size_t qoff = ((size_t)bh * S_LEN + qbase + u * 32 + lid) * HDIM + half * 8;
        #pragma unroll
        for (int es = 0; es < 4; ++es) {
            qh[u][es] = *(const bf16x8*)(qhg + qoff + es * 16);
            ql[u][es] = *(const bf16x8*)(qlg + qoff + es * 16);
        }
    }

    f32x16 o[2][2];
    #pragma unroll
    for (int u = 0; u < 2; ++u)
        #pragma unroll
        for (int d = 0; d < 2; ++d)
            #pragma unroll
            for (int i = 0; i < 16; ++i) o[u][d][i] = 0.f;
    float ls[2][16];
    #pragma unroll
    for (int u = 0; u < 2; ++u)
        #pragma unroll
        for (int i = 0; i < 16; ++i) ls[u][i] = 0.f;

    const size_t kvo = (size_t)(l * BHEADS + bh) * S_LEN * HDIM;

    for (int kt = 0; kt < 16; ++kt) {
        #pragma unroll
        for (int kc = 0; kc < 2; ++kc) {
            bf16x8 kb[4];
            #pragma unroll
            for (int es = 0; es < 4; ++es)
                kb[es] = *(const bf16x8*)(kh + kvo
                          + (size_t)(kt * 64 + kc * 32 + lid) * HDIM + es * 16 + half * 8);

            f32x16 sa[2];
            #pragma unroll
            for (int u = 0; u < 2; ++u)
                #pragma unroll
                for (int i = 0; i < 16; ++i) sa[u][i] = 0.f;
            #pragma unroll
            for (int es = 0; es < 4; ++es)
                #pragma unroll
                for (int u = 0; u < 2; ++u) {
                    sa[u] = __builtin_amdgcn_mfma_f32_32x32x16_bf16(qh[u][es], kb[es], sa[u], 0, 0, 0);
                    sa[u] = __builtin_amdgcn_mfma_f32_32x32x16_bf16(ql[u][es], kb[es], sa[u], 0, 0, 0);
                }

            bf16x8 vb[2][2];
            #pragma unroll
            for (int ks = 0; ks < 2; ++ks)
                #pragma unroll
                for (int dg = 0; dg < 2; ++dg)
                    vb[ks][dg] = *(const bf16x8*)(vth + kvo
                                  + (size_t)(dg * 32 + lid) * S_LEN
                                  + kt * 64 + kc * 32 + ks * 16 + half * 8);

            // P = exp2(sa); row sums; packed cvt; A-layout LDS write [q][k]
            #pragma unroll
            for (int u = 0; u < 2; ++u) {
                ushort* base = &Pa[(wv * 2 + u) * 1280];
                #pragma unroll
                for (int rr = 0; rr < 16; rr += 2) {
                    const float p0 = fast_exp2(sa[u][rr]);
                    const float p1 = fast_exp2(sa[u][rr + 1]);
                    ls[u][rr]     += p0;
                    ls[u][rr + 1] += p1;
                    const uint pb = pk_bf16(p0, p1);
                    const int q0 = (rr & 3) + 8 * (rr >> 2) + 4 * half;
                    base[q0 * 40 + lid]       = (ushort)pb;
                    base[(q0 + 1) * 40 + lid] = (ushort)(pb >> 16);
                }
            }

            // O += P V  (A-frag = 1 ds_read_b128 per (ks,u))
            #pragma unroll
            for (int ks = 0; ks < 2; ++ks)
                #pragma unroll
                for (int u = 0; u < 2; ++u) {
                    const bf16x8 pf = *(const bf16x8*)
                        &Pa[(wv * 2 + u) * 1280 + lid * 40 + ks * 16 + half * 8];
                    #pragma unroll
                    for (int dg = 0; dg < 2; ++dg)
                        o[u][dg] = __builtin_amdgcn_mfma_f32_32x32x16_bf16(pf, vb[ks][dg], o[u][dg], 0, 0, 0);
                }
        }
    }

    #pragma unroll
    for (int u = 0; u < 2; ++u)
        #pragma unroll
        for (int rr = 0; rr < 16; ++rr) {
            float v = ls[u][rr];
            #pragma unroll
            for (int off = 1; off < 32; off <<= 1) v += __shfl_xor(v, off, 32);
            ls[u][rr] = v;
        }

    // ---- epilogue: plain fp32 stores of this layer's partial ----
    const int b = bh >> 4, hh = bh & 15;
    float* pbase = part + (size_t)l * (ROWS_PL * DMODEL);
    #pragma unroll
    for (int u = 0; u < 2; ++u)
        #pragma unroll
        for (int rr = 0; rr < 16; ++rr) {
            const int q = qbase + u * 32 + 8 * (rr >> 2) + 4 * half + (rr & 3);
            const float sc = wl / ls[u][rr];
            #pragma unroll
            for (int dg = 0; dg < 2; ++dg) {
                const int d = hh * HDIM + dg * 32 + lid;
                pbase[((size_t)q * BATCH + b) * DMODEL + d] = o[u][dg][rr] * sc;
            }
        }
}

// ---------------------------------------------------------------------------
// Sum the 4 layer partials -> bf16 hi plane for the O projection.
// ---------------------------------------------------------------------------
__global__ __launch_bounds__(256)
void sum_y(const float* __restrict__ part, ushort* __restrict__ YH)
{
    const int i = (blockIdx.x * 256 + threadIdx.x) * 8;
    float acc[8];
    #pragma unroll
    for (int c = 0; c < 2; ++c) {
        float4 s = *(const float4*)(part + i + c * 4);
        #pragma unroll
        for (int l = 1; l < LP1; ++l) {
            const float4 p = *(const float4*)(part + (size_t)l * 2097152 + i + c * 4);
            s.x += p.x; s.y += p.y; s.z += p.z; s.w += p.w;
        }
        acc[c * 4 + 0] = s.x; acc[c * 4 + 1] = s.y;
        acc[c * 4 + 2] = s.z; acc[c * 4 + 3] = s.w;
    }
    uint out[4];
    #pragma unroll
    for (int c = 0; c < 4; ++c) out[c] = pk_bf16(acc[c * 2], acc[c * 2 + 1]);
    *(uint4*)(YH + i) = *(uint4*)out;
}

// ---------------------------------------------------------------------------
extern "C" void kernel_launch(void* const* d_in, const int* in_sizes, int n_in,
                              void* d_out, int out_size, void* d_ws, size_t ws_size,
                              hipStream_t stream) {
    const float* x  = (const float*)d_in[0];
    const float* lo = (const float*)d_in[1];
    const float* Wq = (const float*)d_in[2];
    const float* bq = (const float*)d_in[3];
    const float* Wk = (const float*)d_in[4];
    const float* bk = (const float*)d_in[5];
    const float* Wv = (const float*)d_in[6];
    const float* bv = (const float*)d_in[7];
    const float* Wo = (const float*)d_in[8];
    const float* bo = (const float*)d_in[9];
    const float* lw = (const float*)d_in[10];
    float* out = (float*)d_out;

    char* ws = (char*)d_ws;
    ushort* XsH  = (ushort*)(ws);                          // 16,777,216 B
    ushort* WH   = (ushort*)(ws + 16777216);               //  8,388,608 B
    ushort* WL   = (ushort*)(ws + 25165824);               //  8,388,608 B (Wq/Wo only)
    ushort* qhb  = (ushort*)(ws + 33554432);               //  4,194,304 B
    ushort* qlb  = (ushort*)(ws + 37748736);               //  4,194,304 B
    ushort* khb  = (ushort*)(ws + 41943040);               // 16,777,216 B
    ushort* vthb = (ushort*)(ws + 58720256);               // 16,777,216 B
    float*  part = (float*)(ws + 75497472);                // 33,554,432 B
    ushort* YH   = (ushort*)(ws + 109051904);              //  4,194,304 B
    // total 113,246,208 B

    dim3 blk(256);
    // Xs -> hi plane; Wq/Wo -> hi+lo; Wk/Wv -> hi only
    presplit<<<dim3(3072, 1, 6), blk, 0, stream>>>(x, lo, Wq, Wk, Wv, Wo, XsH, WH, WL);
    // Q projection (glds): pre-scaled hi/lo planes [b*16+h][s][e]
    proj_g<0><<<dim3(512), blk, 0, stream>>>(XsH, WH, WL, bq, nullptr, qhb, qlb);
    // fused K+V projection (glds, hi-only weights)
    proj_kv<<<dim3(8, 128), blk, 0, stream>>>(XsH,
        WH + 1048576, WH + 2097152, bk, bv, khb, vthb);
    // attention: 512 XCD-swizzled blocks -> per-layer fp32 partials
    attn_mfma<<<dim3(512), blk, 0, stream>>>(qhb, qlb, khb, vthb, lw, part);
    // reduce 4 partials -> bf16 hi plane
    sum_y<<<dim3(1024), blk, 0, stream>>>(part, YH);
    // output projection (glds)
    proj_g<1><<<dim3(512), blk, 0, stream>>>(YH, WH + 3145728, WL + 3145728, bo, out, nullptr, nullptr);
}